// Round 9
// baseline (51916.766 us; speedup 1.0000x reference)
//
#include <hip/hip_runtime.h>

#define B_ 64
#define T_ 512
#define IN0_ 512
#define H_ 1024
#define C_ 1000
#define NWG 256
#define NTHR 384

typedef _Float16 f16;
typedef _Float16 f16x8 __attribute__((ext_vector_type(8)));
typedef _Float16 f16x4 __attribute__((ext_vector_type(4)));
typedef float f32x4 __attribute__((ext_vector_type(4)));

struct Args {
  const float* x;
  const float* Wih[4];
  const float* Whh[4];
  const float* bih[4];
  const float* bhh[4];
  const float* fcw;
  const float* fcb;
  float* out;
  f16* wpack;
  f16* x16;     // [T][B][512] f16
  f16* houts;   // [4 layers][2 parity][64][1024] f16
  float* h32;   // [4 layers][64][1024] f32 master hidden (R6-verified RMW path)
  int* flags;   // NWG padded flags; flags[NWG*32] = go word
};

__device__ __forceinline__ float sigmoid_f(float x) {
  return 1.0f / (1.0f + __expf(-x));
}
__device__ __forceinline__ float tanh_f(float x) {
  return 1.0f - 2.0f / (__expf(2.0f * x) + 1.0f);
}

// Flags barrier with FULL __threadfence() on both sides (R4 protocol —
// exonerated: R4 and R5 produced bit-identical outputs under different
// arrival schemes, so the flags arrival synchronizes correctly; the full
// agent fences are the R1/R6-HW-verified coherence recipe).
__device__ __forceinline__ void grid_barrier(int* flags, int step) {
  int* go = flags + NWG * 32;
  __threadfence();                 // release: drain + push stores device-visible
  __syncthreads();
  if (blockIdx.x == 0) {
    const int t = threadIdx.x;
    if (t > 0 && t < NWG) {        // thread t monitors WG t; WG0 implicit
      while (__hip_atomic_load(flags + t * 32, __ATOMIC_RELAXED,
                               __HIP_MEMORY_SCOPE_AGENT) < step)
        __builtin_amdgcn_s_sleep(1);
    }
    __syncthreads();
    if (t == 0)
      __hip_atomic_store(go, step, __ATOMIC_RELEASE, __HIP_MEMORY_SCOPE_AGENT);
  } else {
    if (threadIdx.x == 0) {
      __hip_atomic_store(flags + blockIdx.x * 32, step, __ATOMIC_RELEASE,
                         __HIP_MEMORY_SCOPE_AGENT);
      while (__hip_atomic_load(go, __ATOMIC_RELAXED,
                               __HIP_MEMORY_SCOPE_AGENT) < step)
        __builtin_amdgcn_s_sleep(1);
    }
  }
  __syncthreads();
  __threadfence();                 // acquire: invalidate stale L1/L2 lines
}

// Packed-weight layer offsets in f16 elements (R6-verified repack layout).
__constant__ __device__ const size_t WOFF_[4] = {0ul, 4718592ul, 11010048ul, 17301504ul};

// LDS slot: bank in 0..7 ({R,Z,NX,NH} x {half0,half1} = {0,1},{2,3},{4,5},{6,7}),
// rb row-block 0..3, i acc element 0..3, + lane. Stride-4B in lane: conflict-free.
__device__ __forceinline__ int ridx(int bank, int rb, int i, int lane) {
  return ((bank * 4 + rb) * 4 + i) * 64 + lane;
}

// Split: wave w (0..5) = (gate g = w>>1, K-half h = w&1). Weights for the
// wave's (gate, half) live in VGPRs (<=32 f16x8 frags, gathered once from the
// R6-verified wpack). Each wave computes partials for ALL 4 row-blocks over
// its K-half; scalar-f32 LDS reduction; waves 0..3 finish rows [16w,16w+16)
// via the R6-verified epilogue (global h32 RMW).
template <int IN>
__device__ void run_layer(const Args& a, int layer, int sub, float* red) {
  constexpr int NKB = (IN + H_) / 32;   // 48 (layer0) or 64
  constexpr int NXB = IN / 32;          // 16 or 32
  constexpr int HALF = NKB / 2;         // 24 or 32

  const int tid = threadIdx.x;
  const int wave = tid >> 6;            // 0..5
  const int lane = tid & 63;
  const int jc = lane & 15;
  const int kg = lane >> 4;
  const int j = sub * 16 + jc;
  const int g = wave >> 1;              // 0=R, 1=Z, 2=N
  const int h = wave & 1;               // K-half
  const int kbase = h * HALF;

  const float bir = a.bih[layer][j], bhr = a.bhh[layer][j];
  const float biz = a.bih[layer][H_ + j], bhz = a.bhh[layer][H_ + j];
  const float bin_ = a.bih[layer][2 * H_ + j], bhn = a.bhh[layer][2 * H_ + j];

  // ---- gather this wave's (gate, half) weight fragments into VGPRs ----
  // wp[(kb)*64] are bitwise the fragments the R6-verified loop streamed.
  const f16x8* wp = (const f16x8*)(a.wpack + WOFF_[layer] +
                                   (size_t)sub * 3 * NKB * 512) +
                    (size_t)g * NKB * 64 + lane;
  f16x8 wf[HALF];
#pragma unroll
  for (int kk = 0; kk < HALF; ++kk) wf[kk] = wp[(size_t)(kbase + kk) * 64];

  f16* hout0 = a.houts + (size_t)(layer * 2 + 0) * B_ * H_;
  f16* hout1 = hout0 + B_ * H_;
  const f16* xp0 = layer ? a.houts + (size_t)((layer - 1) * 2) * B_ * H_ : (const f16*)nullptr;
  const f16* xp1 = layer ? xp0 + B_ * H_ : (const f16*)nullptr;
  float* h32l = a.h32 + (size_t)layer * B_ * H_;

  int step = 2;                          // prologue barrier was step 1

  for (int u = 0; u < T_ + 3; ++u) {
    const int t = u - layer;
    if (t >= 0 && t < T_) {
      const f16* xbase = (IN == IN0_) ? (a.x16 + (size_t)t * B_ * IN0_)
                                      : ((t & 1) ? xp1 : xp0);
      const f16* hbase = ((t + 1) & 1) ? hout1 : hout0;
      f16* ho = (t & 1) ? hout1 : hout0;

      if (g < 2) {
        // R or Z gate: single accumulator over the wave's K-half.
        f32x4 acc[4];
#pragma unroll
        for (int rb = 0; rb < 4; ++rb) acc[rb] = 0.f;
#pragma unroll
        for (int rb = 0; rb < 4; ++rb) {
          const int arow = rb * 16 + jc;
          const f16* xrow = xbase + (size_t)arow * IN + kg * 8;
          const f16* hrow = hbase + (size_t)arow * H_ + kg * 8;
#pragma unroll
          for (int kk = 0; kk < HALF; ++kk) {
            const int kb = kbase + kk;
            const f16* ap = (kb < NXB) ? (xrow + kb * 32)
                                       : (hrow + (kb - NXB) * 32);
            acc[rb] = __builtin_amdgcn_mfma_f32_16x16x32_f16(
                *(const f16x8*)ap, wf[kk], acc[rb], 0, 0, 0);
          }
        }
        const int bank = g * 2 + h;      // R: 0/1, Z: 2/3
#pragma unroll
        for (int rb = 0; rb < 4; ++rb)
#pragma unroll
          for (int i = 0; i < 4; ++i)
            red[ridx(bank, rb, i, lane)] = acc[rb][i];
      } else {
        // N gate: x-part and h-part must accumulate separately. Masked-operand
        // MFMA keeps it branch-free: contribution goes to exactly one acc.
        f32x4 ax[4], ah[4];
#pragma unroll
        for (int rb = 0; rb < 4; ++rb) { ax[rb] = 0.f; ah[rb] = 0.f; }
#pragma unroll
        for (int rb = 0; rb < 4; ++rb) {
          const int arow = rb * 16 + jc;
          const f16* xrow = xbase + (size_t)arow * IN + kg * 8;
          const f16* hrow = hbase + (size_t)arow * H_ + kg * 8;
#pragma unroll
          for (int kk = 0; kk < HALF; ++kk) {
            const int kb = kbase + kk;
            const bool isx = kb < NXB;   // wave-uniform
            const f16* ap = isx ? (xrow + kb * 32) : (hrow + (kb - NXB) * 32);
            const f16x8 af = *(const f16x8*)ap;
            const f16x8 z8 = {0, 0, 0, 0, 0, 0, 0, 0};
            const f16x8 afx = isx ? af : z8;
            const f16x8 afh = isx ? z8 : af;
            ax[rb] = __builtin_amdgcn_mfma_f32_16x16x32_f16(afx, wf[kk], ax[rb], 0, 0, 0);
            ah[rb] = __builtin_amdgcn_mfma_f32_16x16x32_f16(afh, wf[kk], ah[rb], 0, 0, 0);
          }
        }
#pragma unroll
        for (int rb = 0; rb < 4; ++rb)
#pragma unroll
          for (int i = 0; i < 4; ++i) {
            red[ridx(4 + h, rb, i, lane)] = ax[rb][i];
            red[ridx(6 + h, rb, i, lane)] = ah[rb][i];
          }
      }

      __syncthreads();

      if (wave < 4) {
        // R6-verified epilogue shape: wave w finishes rows [16w, 16w+16),
        // b = 16w + kg*4 + i, j = sub*16 + jc; h via global h32 RMW.
#pragma unroll
        for (int i = 0; i < 4; ++i) {
          const int b = wave * 16 + kg * 4 + i;
          const float R  = red[ridx(0, wave, i, lane)] + red[ridx(1, wave, i, lane)];
          const float Z  = red[ridx(2, wave, i, lane)] + red[ridx(3, wave, i, lane)];
          const float NX = red[ridx(4, wave, i, lane)] + red[ridx(5, wave, i, lane)];
          const float NH = red[ridx(6, wave, i, lane)] + red[ridx(7, wave, i, lane)];
          const float r = sigmoid_f(R + bir + bhr);
          const float zz = sigmoid_f(Z + biz + bhz);
          const float nn = tanh_f(NX + bin_ + r * (NH + bhn));
          const float hp = h32l[(size_t)b * H_ + j];
          const float hnew = (1.0f - zz) * nn + zz * hp;
          h32l[(size_t)b * H_ + j] = hnew;
          ho[(size_t)b * H_ + j] = (f16)hnew;
        }
      }
    }
    grid_barrier(a.flags, step++);
  }
}

__global__ void __launch_bounds__(NTHR, 2) gru_pipeline(Args a) {
  __shared__ float red[8 * 4 * 4 * 64];   // 32 KiB, scalar f32

  const int tid = threadIdx.x;
  const int gtid = blockIdx.x * NTHR + tid;
  const int NT = NWG * NTHR;

  // ================= Phase 0: prologue (R6 verbatim logic) ================
  {
    const int nf4 = B_ * T_ * IN0_ / 4;
    for (int i = gtid; i < nf4; i += NT) {
      int k4 = i & 127;
      int q = i >> 7;
      int b = q & 63;
      int t = q >> 6;
      const float4 v = *(const float4*)(a.x + ((size_t)b * T_ + t) * IN0_ + k4 * 4);
      f16x4 o;
      o[0] = (f16)v.x; o[1] = (f16)v.y; o[2] = (f16)v.z; o[3] = (f16)v.w;
      *(f16x4*)(a.x16 + (size_t)i * 4) = o;
    }
  }
  {
    f16x8 z8 = {0, 0, 0, 0, 0, 0, 0, 0};
    for (int i = gtid; i < 4 * 2 * B_ * H_ / 8; i += NT)
      ((f16x8*)a.houts)[i] = z8;
    f32x4 z4 = {0, 0, 0, 0};
    for (int i = gtid; i < 4 * B_ * H_ / 4; i += NT)
      ((f32x4*)a.h32)[i] = z4;
  }
  for (int l = 0; l < 4; ++l) {
    const int In = l ? H_ : IN0_;
    const int K = In + H_;
    const int NKB = K / 32;
    const float* Wih = a.Wih[l];
    const float* Whh = a.Whh[l];
    f16* wp = a.wpack + WOFF_[l];
    const int nunits = 3 * H_ * K / 8;
    for (int uu = gtid; uu < nunits; uu += NT) {
      int lane = uu & 63;
      int q = uu >> 6;
      int kb = q % NKB; q /= NKB;
      int gate = q % 3;
      int subb = q / 3;
      int j = subb * 16 + (lane & 15);
      int g = gate * H_ + j;
      int k = kb * 32 + (lane >> 4) * 8;
      const float* src = (k < In) ? (Wih + (size_t)g * In + k)
                                  : (Whh + (size_t)g * H_ + (k - In));
      f16x8 vv;
#pragma unroll
      for (int e = 0; e < 8; ++e) vv[e] = (f16)src[e];
      ((f16x8*)wp)[uu] = vv;
    }
  }

  grid_barrier(a.flags, 1);

  // ================= Phase 1: pipelined recurrence ========================
  const int wg = blockIdx.x;
  const int layer = wg >> 6;
  const int sub = wg & 63;

  if (layer == 0) run_layer<IN0_>(a, layer, sub, red);
  else            run_layer<H_>(a, layer, sub, red);

  // ================= Phase 2: final FC (R6 verbatim) =====================
  for (int o = gtid; o < B_ * C_; o += NT) {
    const int b = o / C_;
    const int c = o - b * C_;
    const float* hv = a.h32 + (size_t)3 * B_ * H_ + (size_t)b * H_;
    const float* wv = a.fcw + (size_t)c * H_;
    float s = a.fcb[c];
    for (int k = 0; k < H_; k += 4) {
      const float4 h4 = *(const float4*)(hv + k);
      const float4 w4 = *(const float4*)(wv + k);
      s = fmaf(h4.x, w4.x, s);
      s = fmaf(h4.y, w4.y, s);
      s = fmaf(h4.z, w4.z, s);
      s = fmaf(h4.w, w4.w, s);
    }
    a.out[o] = s;
  }
}

extern "C" void kernel_launch(void* const* d_in, const int* in_sizes, int n_in,
                              void* d_out, int out_size, void* d_ws, size_t ws_size,
                              hipStream_t stream) {
  Args a;
  a.x = (const float*)d_in[0];
  for (int l = 0; l < 4; ++l) {
    a.Wih[l] = (const float*)d_in[1 + 4 * l];
    a.Whh[l] = (const float*)d_in[2 + 4 * l];
    a.bih[l] = (const float*)d_in[3 + 4 * l];
    a.bhh[l] = (const float*)d_in[4 + 4 * l];
  }
  a.fcw = (const float*)d_in[17];
  a.fcb = (const float*)d_in[18];
  a.out = (float*)d_out;

  char* ws = (char*)d_ws;
  size_t off = 0;
  a.wpack = (f16*)(ws + off); off += 23592960ul * 2;                  // 45 MiB
  a.x16   = (f16*)(ws + off); off += 16777216ul * 2;                  // 32 MiB
  a.houts = (f16*)(ws + off); off += 4ul * 2 * B_ * H_ * 2;           // 1 MiB
  a.h32   = (float*)(ws + off); off += 4ul * B_ * H_ * 4;             // 1 MiB
  a.flags = (int*)(ws + off); off += (NWG * 32 + 32) * sizeof(int);   // 33 KiB

  hipMemsetAsync(a.flags, 0, (NWG * 32 + 32) * sizeof(int), stream);

  void* params[] = { &a };
  hipError_t err = hipLaunchCooperativeKernel((void*)gru_pipeline, dim3(NWG),
                                              dim3(NTHR), params, 0, stream);
  if (err != hipSuccess) {
    gru_pipeline<<<dim3(NWG), dim3(NTHR), 0, stream>>>(a);
  }
}

// Round 10
// 43058.838 us; speedup vs baseline: 1.2057x; 1.2057x over previous
//
#include <hip/hip_runtime.h>

#define B_ 64
#define T_ 512
#define IN0_ 512
#define H_ 1024
#define C_ 1000
#define NWG 256
#define NTHR 384

typedef _Float16 f16;
typedef _Float16 f16x8 __attribute__((ext_vector_type(8)));
typedef _Float16 f16x4 __attribute__((ext_vector_type(4)));
typedef float f32x4 __attribute__((ext_vector_type(4)));

struct Args {
  const float* x;
  const float* Wih[4];
  const float* Whh[4];
  const float* bih[4];
  const float* bhh[4];
  const float* fcw;
  const float* fcb;
  float* out;
  f16* wpack;
  f16* x16;     // [T][B][512] f16
  f16* houts;   // [4 layers][2 parity][64][1024] f16
  float* h32;   // [4 layers][64][1024] f32 master hidden (self RMW)
  int* flags;   // NWG padded flags; flags[NWG*32] = go word (light barrier)
  int* bar;     // [0]=count, [1]=generation (heavy barrier)
};

__device__ __forceinline__ float sigmoid_f(float x) {
  return 1.0f / (1.0f + __expf(-x));
}
__device__ __forceinline__ float tanh_f(float x) {
  return 1.0f - 2.0f / (__expf(2.0f * x) + 1.0f);
}

// HEAVY barrier — R1 VERBATIM (HW-verified). Full agent fences both sides.
// Used only twice (post-prologue, pre-FC).
__device__ __forceinline__ void heavy_barrier(int* bar) {
  __threadfence();
  __syncthreads();
  if (threadIdx.x == 0) {
    int* cnt = bar;
    int* gen = bar + 1;
    int g = __hip_atomic_load(gen, __ATOMIC_RELAXED, __HIP_MEMORY_SCOPE_AGENT);
    int v = __hip_atomic_fetch_add(cnt, 1, __ATOMIC_ACQ_REL, __HIP_MEMORY_SCOPE_AGENT);
    if (v == NWG - 1) {
      __hip_atomic_store(cnt, 0, __ATOMIC_RELAXED, __HIP_MEMORY_SCOPE_AGENT);
      __hip_atomic_store(gen, g + 1, __ATOMIC_RELEASE, __HIP_MEMORY_SCOPE_AGENT);
    } else {
      int cur;
      do {
        __builtin_amdgcn_s_sleep(2);
        cur = __hip_atomic_load(gen, __ATOMIC_ACQUIRE, __HIP_MEMORY_SCOPE_AGENT);
      } while (cur == g);
    }
  }
  __syncthreads();
  __threadfence();
}

// LIGHT per-step barrier — R8 VERBATIM (HW-verified PASS). Release side only:
// fence(release,agent) pushes this step's ho/h32 stores to the memory-side L3;
// no acquire fence (keeps L1/L2 warm). Consumers read shared data via sc1
// (agent-scope) atomic loads served at L3.
__device__ __forceinline__ void light_barrier(int* flags, int step) {
  int* go = flags + NWG * 32;
  __builtin_amdgcn_fence(__ATOMIC_RELEASE, "agent");
  __syncthreads();
  if (blockIdx.x == 0) {
    const int t = threadIdx.x;
    if (t > 0 && t < NWG) {        // thread t monitors WG t; WG0 implicit
      while (__hip_atomic_load(flags + t * 32, __ATOMIC_RELAXED,
                               __HIP_MEMORY_SCOPE_AGENT) < step)
        __builtin_amdgcn_s_sleep(1);
    }
    __syncthreads();
    if (t == 0)
      __hip_atomic_store(go, step, __ATOMIC_RELAXED, __HIP_MEMORY_SCOPE_AGENT);
  } else {
    if (threadIdx.x == 0) {
      __hip_atomic_store(flags + blockIdx.x * 32, step, __ATOMIC_RELAXED,
                         __HIP_MEMORY_SCOPE_AGENT);
      while (__hip_atomic_load(go, __ATOMIC_RELAXED,
                               __HIP_MEMORY_SCOPE_AGENT) < step)
        __builtin_amdgcn_s_sleep(1);
    }
  }
  __syncthreads();
}

// Coherent 16B fragment load — R8 VERBATIM (HW-verified): two relaxed
// agent-scope 8B atomic loads (sc1, bypass possibly-stale L1/L2, served at
// the always-coherent memory-side L3).
union U16B { unsigned long long u[2]; f16x8 v; };
__device__ __forceinline__ f16x8 aload16(const f16* p) {
  unsigned long long* q = (unsigned long long*)p;
  U16B r;
  r.u[0] = __hip_atomic_load(q,     __ATOMIC_RELAXED, __HIP_MEMORY_SCOPE_AGENT);
  r.u[1] = __hip_atomic_load(q + 1, __ATOMIC_RELAXED, __HIP_MEMORY_SCOPE_AGENT);
  return r.v;
}

// Packed-weight layer offsets in f16 elements (R6-verified repack layout).
__constant__ __device__ const size_t WOFF_[4] = {0ul, 4718592ul, 11010048ul, 17301504ul};

// LDS reduction slot (R9-verified scalar layout).
__device__ __forceinline__ int ridx(int bank, int rb, int i, int lane) {
  return ((bank * 4 + rb) * 4 + i) * 64 + lane;
}

// R9-VERIFIED split-K layer. Changes vs R9: activation fragments load via
// aload16 (XA selects x-side), per-step light barrier. Nothing else.
template <int IN, bool XA>
__device__ void run_layer(const Args& a, int layer, int sub, float* red) {
  constexpr int NKB = (IN + H_) / 32;   // 48 (layer0) or 64
  constexpr int NXB = IN / 32;          // 16 or 32
  constexpr int HALF = NKB / 2;         // 24 or 32

  const int tid = threadIdx.x;
  const int wave = tid >> 6;            // 0..5
  const int lane = tid & 63;
  const int jc = lane & 15;
  const int kg = lane >> 4;
  const int j = sub * 16 + jc;
  const int g = wave >> 1;              // 0=R, 1=Z, 2=N
  const int h = wave & 1;               // K-half
  const int kbase = h * HALF;

  const float bir = a.bih[layer][j], bhr = a.bhh[layer][j];
  const float biz = a.bih[layer][H_ + j], bhz = a.bhh[layer][H_ + j];
  const float bin_ = a.bih[layer][2 * H_ + j], bhn = a.bhh[layer][2 * H_ + j];

  // ---- gather this wave's (gate, half) weight fragments into VGPRs ----
  const f16x8* wp = (const f16x8*)(a.wpack + WOFF_[layer] +
                                   (size_t)sub * 3 * NKB * 512) +
                    (size_t)g * NKB * 64 + lane;
  f16x8 wf[HALF];
#pragma unroll
  for (int kk = 0; kk < HALF; ++kk) wf[kk] = wp[(size_t)(kbase + kk) * 64];

  f16* hout0 = a.houts + (size_t)(layer * 2 + 0) * B_ * H_;
  f16* hout1 = hout0 + B_ * H_;
  const f16* xp0 = layer ? a.houts + (size_t)((layer - 1) * 2) * B_ * H_ : (const f16*)nullptr;
  const f16* xp1 = layer ? xp0 + B_ * H_ : (const f16*)nullptr;
  float* h32l = a.h32 + (size_t)layer * B_ * H_;

  for (int u = 0; u < T_ + 3; ++u) {
    const int t = u - layer;
    if (t >= 0 && t < T_) {
      const f16* xbase = (IN == IN0_) ? (a.x16 + (size_t)t * B_ * IN0_)
                                      : ((t & 1) ? xp1 : xp0);
      const f16* hbase = ((t + 1) & 1) ? hout1 : hout0;
      f16* ho = (t & 1) ? hout1 : hout0;

      if (g < 2) {
        f32x4 acc[4];
#pragma unroll
        for (int rb = 0; rb < 4; ++rb) acc[rb] = 0.f;
#pragma unroll
        for (int rb = 0; rb < 4; ++rb) {
          const int arow = rb * 16 + jc;
          const f16* xrow = xbase + (size_t)arow * IN + kg * 8;
          const f16* hrow = hbase + (size_t)arow * H_ + kg * 8;
#pragma unroll
          for (int kk = 0; kk < HALF; ++kk) {
            const int kb = kbase + kk;
            f16x8 af;
            if (kb < NXB) {
              if constexpr (XA) af = aload16(xrow + kb * 32);
              else              af = *(const f16x8*)(xrow + kb * 32);
            } else {
              af = aload16(hrow + (kb - NXB) * 32);
            }
            acc[rb] = __builtin_amdgcn_mfma_f32_16x16x32_f16(af, wf[kk], acc[rb], 0, 0, 0);
          }
        }
        const int bank = g * 2 + h;      // R: 0/1, Z: 2/3
#pragma unroll
        for (int rb = 0; rb < 4; ++rb)
#pragma unroll
          for (int i = 0; i < 4; ++i)
            red[ridx(bank, rb, i, lane)] = acc[rb][i];
      } else {
        // N gate: x/h parts separate via masked-operand MFMA (R9-verified).
        f32x4 ax[4], ah[4];
#pragma unroll
        for (int rb = 0; rb < 4; ++rb) { ax[rb] = 0.f; ah[rb] = 0.f; }
#pragma unroll
        for (int rb = 0; rb < 4; ++rb) {
          const int arow = rb * 16 + jc;
          const f16* xrow = xbase + (size_t)arow * IN + kg * 8;
          const f16* hrow = hbase + (size_t)arow * H_ + kg * 8;
#pragma unroll
          for (int kk = 0; kk < HALF; ++kk) {
            const int kb = kbase + kk;
            const bool isx = kb < NXB;   // wave-uniform, compile-time
            f16x8 af;
            if (isx) {
              if constexpr (XA) af = aload16(xrow + kb * 32);
              else              af = *(const f16x8*)(xrow + kb * 32);
            } else {
              af = aload16(hrow + (kb - NXB) * 32);
            }
            const f16x8 z8 = {0, 0, 0, 0, 0, 0, 0, 0};
            const f16x8 afx = isx ? af : z8;
            const f16x8 afh = isx ? z8 : af;
            ax[rb] = __builtin_amdgcn_mfma_f32_16x16x32_f16(afx, wf[kk], ax[rb], 0, 0, 0);
            ah[rb] = __builtin_amdgcn_mfma_f32_16x16x32_f16(afh, wf[kk], ah[rb], 0, 0, 0);
          }
        }
#pragma unroll
        for (int rb = 0; rb < 4; ++rb)
#pragma unroll
          for (int i = 0; i < 4; ++i) {
            red[ridx(4 + h, rb, i, lane)] = ax[rb][i];
            red[ridx(6 + h, rb, i, lane)] = ah[rb][i];
          }
      }

      __syncthreads();

      if (wave < 4) {
        // R6/R9-verified epilogue: wave w finishes rows [16w,16w+16).
#pragma unroll
        for (int i = 0; i < 4; ++i) {
          const int b = wave * 16 + kg * 4 + i;
          const float R  = red[ridx(0, wave, i, lane)] + red[ridx(1, wave, i, lane)];
          const float Z  = red[ridx(2, wave, i, lane)] + red[ridx(3, wave, i, lane)];
          const float NX = red[ridx(4, wave, i, lane)] + red[ridx(5, wave, i, lane)];
          const float NH = red[ridx(6, wave, i, lane)] + red[ridx(7, wave, i, lane)];
          const float r = sigmoid_f(R + bir + bhr);
          const float zz = sigmoid_f(Z + biz + bhz);
          const float nn = tanh_f(NX + bin_ + r * (NH + bhn));
          const float hp = h32l[(size_t)b * H_ + j];
          const float hnew = (1.0f - zz) * nn + zz * hp;
          h32l[(size_t)b * H_ + j] = hnew;
          ho[(size_t)b * H_ + j] = (f16)hnew;
        }
      }
    }
    light_barrier(a.flags, u + 1);
  }
}

__global__ void __launch_bounds__(NTHR, 1) gru_pipeline(Args a) {
  __shared__ float red[8 * 4 * 4 * 64];   // 32 KiB scalar f32 (R9-verified)

  const int tid = threadIdx.x;
  const int gtid = blockIdx.x * NTHR + tid;
  const int NT = NWG * NTHR;

  // ================= Phase 0: prologue (R6/R9 verbatim) ===================
  {
    const int nf4 = B_ * T_ * IN0_ / 4;
    for (int i = gtid; i < nf4; i += NT) {
      int k4 = i & 127;
      int q = i >> 7;
      int b = q & 63;
      int t = q >> 6;
      const float4 v = *(const float4*)(a.x + ((size_t)b * T_ + t) * IN0_ + k4 * 4);
      f16x4 o;
      o[0] = (f16)v.x; o[1] = (f16)v.y; o[2] = (f16)v.z; o[3] = (f16)v.w;
      *(f16x4*)(a.x16 + (size_t)i * 4) = o;
    }
  }
  {
    f16x8 z8 = {0, 0, 0, 0, 0, 0, 0, 0};
    for (int i = gtid; i < 4 * 2 * B_ * H_ / 8; i += NT)
      ((f16x8*)a.houts)[i] = z8;
    f32x4 z4 = {0, 0, 0, 0};
    for (int i = gtid; i < 4 * B_ * H_ / 4; i += NT)
      ((f32x4*)a.h32)[i] = z4;
  }
  for (int l = 0; l < 4; ++l) {
    const int In = l ? H_ : IN0_;
    const int K = In + H_;
    const int NKB = K / 32;
    const float* Wih = a.Wih[l];
    const float* Whh = a.Whh[l];
    f16* wp = a.wpack + WOFF_[l];
    const int nunits = 3 * H_ * K / 8;
    for (int uu = gtid; uu < nunits; uu += NT) {
      int lane = uu & 63;
      int q = uu >> 6;
      int kb = q % NKB; q /= NKB;
      int gate = q % 3;
      int subb = q / 3;
      int j = subb * 16 + (lane & 15);
      int g = gate * H_ + j;
      int k = kb * 32 + (lane >> 4) * 8;
      const float* src = (k < In) ? (Wih + (size_t)g * In + k)
                                  : (Whh + (size_t)g * H_ + (k - In));
      f16x8 vv;
#pragma unroll
      for (int e = 0; e < 8; ++e) vv[e] = (f16)src[e];
      ((f16x8*)wp)[uu] = vv;
    }
  }

  heavy_barrier(a.bar);   // full flush+invalidate once: x16/wpack now stable

  // ================= Phase 1: pipelined recurrence ========================
  const int wg = blockIdx.x;
  const int layer = wg >> 6;
  const int sub = wg & 63;

  if (layer == 0) run_layer<IN0_, false>(a, layer, sub, red);
  else            run_layer<H_, true>(a, layer, sub, red);

  heavy_barrier(a.bar);   // full visibility for h32 before FC

  // ================= Phase 2: final FC (R6/R9 verbatim) ==================
  for (int o = gtid; o < B_ * C_; o += NT) {
    const int b = o / C_;
    const int c = o - b * C_;
    const float* hv = a.h32 + (size_t)3 * B_ * H_ + (size_t)b * H_;
    const float* wv = a.fcw + (size_t)c * H_;
    float s = a.fcb[c];
    for (int k = 0; k < H_; k += 4) {
      const float4 h4 = *(const float4*)(hv + k);
      const float4 w4 = *(const float4*)(wv + k);
      s = fmaf(h4.x, w4.x, s);
      s = fmaf(h4.y, w4.y, s);
      s = fmaf(h4.z, w4.z, s);
      s = fmaf(h4.w, w4.w, s);
    }
    a.out[o] = s;
  }
}

extern "C" void kernel_launch(void* const* d_in, const int* in_sizes, int n_in,
                              void* d_out, int out_size, void* d_ws, size_t ws_size,
                              hipStream_t stream) {
  Args a;
  a.x = (const float*)d_in[0];
  for (int l = 0; l < 4; ++l) {
    a.Wih[l] = (const float*)d_in[1 + 4 * l];
    a.Whh[l] = (const float*)d_in[2 + 4 * l];
    a.bih[l] = (const float*)d_in[3 + 4 * l];
    a.bhh[l] = (const float*)d_in[4 + 4 * l];
  }
  a.fcw = (const float*)d_in[17];
  a.fcb = (const float*)d_in[18];
  a.out = (float*)d_out;

  char* ws = (char*)d_ws;
  size_t off = 0;
  a.wpack = (f16*)(ws + off); off += 23592960ul * 2;                  // 45 MiB
  a.x16   = (f16*)(ws + off); off += 16777216ul * 2;                  // 32 MiB
  a.houts = (f16*)(ws + off); off += 4ul * 2 * B_ * H_ * 2;           // 1 MiB
  a.h32   = (float*)(ws + off); off += 4ul * B_ * H_ * 4;             // 1 MiB
  a.flags = (int*)(ws + off); off += (NWG * 32 + 32) * sizeof(int);   // 33 KiB
  a.bar   = (int*)(ws + off); off += 256;

  hipMemsetAsync(a.flags, 0, (NWG * 32 + 32) * sizeof(int) + 256, stream);

  void* params[] = { &a };
  hipError_t err = hipLaunchCooperativeKernel((void*)gru_pipeline, dim3(NWG),
                                              dim3(NTHR), params, 0, stream);
  if (err != hipSuccess) {
    gru_pipeline<<<dim3(NWG), dim3(NTHR), 0, stream>>>(a);
  }
}

// Round 11
// 24351.509 us; speedup vs baseline: 2.1320x; 1.7682x over previous
//
#include <hip/hip_runtime.h>

#define B_ 64
#define T_ 512
#define IN0_ 512
#define H_ 1024
#define C_ 1000
#define NWG 256
#define NTHR 256

typedef _Float16 f16;
typedef _Float16 f16x8 __attribute__((ext_vector_type(8)));
typedef _Float16 f16x4 __attribute__((ext_vector_type(4)));
typedef float f32x4 __attribute__((ext_vector_type(4)));

struct Args {
  const float* x;
  const float* Wih[4];
  const float* Whh[4];
  const float* bih[4];
  const float* bhh[4];
  const float* fcw;
  const float* fcb;
  float* out;
  f16* wpack;
  f16* x16;     // [T][B][512] f16
  f16* houts;   // [4 layers][2 parity][64][1024] f16
  float* h32;   // [4 layers][64][1024] f32 master hidden (self RMW)
  int* flags;   // NWG padded flags; flags[NWG*32] = go word (light barrier)
  int* bar;     // [0]=count, [1]=generation (heavy barrier)
};

__device__ __forceinline__ float sigmoid_f(float x) {
  return 1.0f / (1.0f + __expf(-x));
}
__device__ __forceinline__ float tanh_f(float x) {
  return 1.0f - 2.0f / (__expf(2.0f * x) + 1.0f);
}

// HEAVY barrier — R1 VERBATIM (HW-verified). Used twice only.
__device__ __forceinline__ void heavy_barrier(int* bar) {
  __threadfence();
  __syncthreads();
  if (threadIdx.x == 0) {
    int* cnt = bar;
    int* gen = bar + 1;
    int g = __hip_atomic_load(gen, __ATOMIC_RELAXED, __HIP_MEMORY_SCOPE_AGENT);
    int v = __hip_atomic_fetch_add(cnt, 1, __ATOMIC_ACQ_REL, __HIP_MEMORY_SCOPE_AGENT);
    if (v == NWG - 1) {
      __hip_atomic_store(cnt, 0, __ATOMIC_RELAXED, __HIP_MEMORY_SCOPE_AGENT);
      __hip_atomic_store(gen, g + 1, __ATOMIC_RELEASE, __HIP_MEMORY_SCOPE_AGENT);
    } else {
      int cur;
      do {
        __builtin_amdgcn_s_sleep(2);
        cur = __hip_atomic_load(gen, __ATOMIC_ACQUIRE, __HIP_MEMORY_SCOPE_AGENT);
      } while (cur == g);
    }
  }
  __syncthreads();
  __threadfence();
}

// LIGHT per-step barrier — R8/R10 VERBATIM (HW-verified PASS).
__device__ __forceinline__ void light_barrier(int* flags, int step) {
  int* go = flags + NWG * 32;
  __builtin_amdgcn_fence(__ATOMIC_RELEASE, "agent");
  __syncthreads();
  if (blockIdx.x == 0) {
    const int t = threadIdx.x;
    if (t > 0 && t < NWG) {
      while (__hip_atomic_load(flags + t * 32, __ATOMIC_RELAXED,
                               __HIP_MEMORY_SCOPE_AGENT) < step)
        __builtin_amdgcn_s_sleep(1);
    }
    __syncthreads();
    if (t == 0)
      __hip_atomic_store(go, step, __ATOMIC_RELAXED, __HIP_MEMORY_SCOPE_AGENT);
  } else {
    if (threadIdx.x == 0) {
      __hip_atomic_store(flags + blockIdx.x * 32, step, __ATOMIC_RELAXED,
                         __HIP_MEMORY_SCOPE_AGENT);
      while (__hip_atomic_load(go, __ATOMIC_RELAXED,
                               __HIP_MEMORY_SCOPE_AGENT) < step)
        __builtin_amdgcn_s_sleep(1);
    }
  }
  __syncthreads();
}

// Coherent 16B fragment load — R8/R10 VERBATIM (HW-verified).
union U16B { unsigned long long u[2]; f16x8 v; };
__device__ __forceinline__ f16x8 aload16(const f16* p) {
  unsigned long long* q = (unsigned long long*)p;
  U16B r;
  r.u[0] = __hip_atomic_load(q,     __ATOMIC_RELAXED, __HIP_MEMORY_SCOPE_AGENT);
  r.u[1] = __hip_atomic_load(q + 1, __ATOMIC_RELAXED, __HIP_MEMORY_SCOPE_AGENT);
  return r.v;
}

// Packed-weight layer offsets in f16 elements (R6-verified repack layout).
__constant__ __device__ const size_t WOFF_[4] = {0ul, 4718592ul, 11010048ul, 17301504ul};

// LDS reduction slot (R9-verified scalar layout; banks R:0/1 Z:2/3 NX:4/5 NH:6/7).
__device__ __forceinline__ int ridx(int bank, int rb, int i, int lane) {
  return ((bank * 4 + rb) * 4 + i) * 64 + lane;
}

// K-slice split: wave w (0..3) owns k-blocks [w*SLICE,(w+1)*SLICE) for ALL 3
// gates (A loaded ONCE per WG per step — 3x traffic cut vs R10). Weights for
// the slice (3 gates x SLICE frags) in VGPRs. Scalar-LDS reduction in two
// phases (waves 0,1 write pair-0/1 banks; waves 2,3 add back). Epilogue =
// R9-verified (wave w finishes rows [16w,16w+16), global h32 RMW).
template <int IN, bool XA>
__device__ void run_layer(const Args& a, int layer, int sub, float* red) {
  constexpr int NKB = (IN + H_) / 32;   // 48 (layer0) or 64
  constexpr int NXB = IN / 32;          // 16 or 32
  constexpr int SLICE = NKB / 4;        // 12 or 16

  const int tid = threadIdx.x;
  const int wave = tid >> 6;            // 0..3
  const int lane = tid & 63;
  const int jc = lane & 15;
  const int kg = lane >> 4;
  const int j = sub * 16 + jc;
  const int wbase = wave * SLICE;

  const float bir = a.bih[layer][j], bhr = a.bhh[layer][j];
  const float biz = a.bih[layer][H_ + j], bhz = a.bhh[layer][H_ + j];
  const float bin_ = a.bih[layer][2 * H_ + j], bhn = a.bhh[layer][2 * H_ + j];

  // ---- gather this wave's K-slice weights, all 3 gates (R9-verified expr) --
  const f16x8* wpb = (const f16x8*)(a.wpack + WOFF_[layer] +
                                    (size_t)sub * 3 * NKB * 512) + lane;
  f16x8 wfR[SLICE], wfZ[SLICE], wfN[SLICE];
#pragma unroll
  for (int kk = 0; kk < SLICE; ++kk) {
    wfR[kk] = wpb[(size_t)(0 * NKB + wbase + kk) * 64];
    wfZ[kk] = wpb[(size_t)(1 * NKB + wbase + kk) * 64];
    wfN[kk] = wpb[(size_t)(2 * NKB + wbase + kk) * 64];
  }

  f16* hout0 = a.houts + (size_t)(layer * 2 + 0) * B_ * H_;
  f16* hout1 = hout0 + B_ * H_;
  const f16* xp0 = layer ? a.houts + (size_t)((layer - 1) * 2) * B_ * H_ : (const f16*)nullptr;
  const f16* xp1 = layer ? xp0 + B_ * H_ : (const f16*)nullptr;
  float* h32l = a.h32 + (size_t)layer * B_ * H_;

  for (int u = 0; u < T_ + 3; ++u) {
    const int t = u - layer;
    if (t >= 0 && t < T_) {
      const f16* xbase = (IN == IN0_) ? (a.x16 + (size_t)t * B_ * IN0_)
                                      : ((t & 1) ? xp1 : xp0);
      const f16* hbase = ((t + 1) & 1) ? hout1 : hout0;
      f16* ho = (t & 1) ? hout1 : hout0;

      f32x4 aR[4], aZ[4], aNX[4], aNH[4];
#pragma unroll
      for (int rb = 0; rb < 4; ++rb) {
        aR[rb] = 0.f; aZ[rb] = 0.f; aNX[rb] = 0.f; aNH[rb] = 0.f;
      }

#pragma unroll
      for (int rb = 0; rb < 4; ++rb) {
        const int arow = rb * 16 + jc;
        const f16* xrow = xbase + (size_t)arow * IN + kg * 8;
        const f16* hrow = hbase + (size_t)arow * H_ + kg * 8;
#pragma unroll
        for (int kk = 0; kk < SLICE; ++kk) {
          const int kb = wbase + kk;
          const bool isx = kb < NXB;     // wave-uniform select (R9-verified)
          f16x8 af;
          if (isx) {
            if constexpr (XA) af = aload16(xrow + kb * 32);
            else              af = *(const f16x8*)(xrow + kb * 32);
          } else {
            af = aload16(hrow + (kb - NXB) * 32);
          }
          aR[rb] = __builtin_amdgcn_mfma_f32_16x16x32_f16(af, wfR[kk], aR[rb], 0, 0, 0);
          aZ[rb] = __builtin_amdgcn_mfma_f32_16x16x32_f16(af, wfZ[kk], aZ[rb], 0, 0, 0);
          const f16x8 z8 = {0, 0, 0, 0, 0, 0, 0, 0};
          const f16x8 afx = isx ? af : z8;   // masked N split (R9-verified)
          const f16x8 afh = isx ? z8 : af;
          aNX[rb] = __builtin_amdgcn_mfma_f32_16x16x32_f16(afx, wfN[kk], aNX[rb], 0, 0, 0);
          aNH[rb] = __builtin_amdgcn_mfma_f32_16x16x32_f16(afh, wfN[kk], aNH[rb], 0, 0, 0);
        }
      }

      // ---- two-phase scalar-LDS reduction (banks: R 0/1, Z 2/3, NX 4/5, NH 6/7)
      if (wave < 2) {                    // phase A: waves 0,1 write pair=wave
#pragma unroll
        for (int rb = 0; rb < 4; ++rb)
#pragma unroll
          for (int i = 0; i < 4; ++i) {
            red[ridx(0 + wave, rb, i, lane)] = aR[rb][i];
            red[ridx(2 + wave, rb, i, lane)] = aZ[rb][i];
            red[ridx(4 + wave, rb, i, lane)] = aNX[rb][i];
            red[ridx(6 + wave, rb, i, lane)] = aNH[rb][i];
          }
      }
      __syncthreads();
      if (wave >= 2) {                   // phase B: waves 2,3 add into pair=wave-2
        const int p = wave - 2;
#pragma unroll
        for (int rb = 0; rb < 4; ++rb)
#pragma unroll
          for (int i = 0; i < 4; ++i) {
            red[ridx(0 + p, rb, i, lane)] += aR[rb][i];
            red[ridx(2 + p, rb, i, lane)] += aZ[rb][i];
            red[ridx(4 + p, rb, i, lane)] += aNX[rb][i];
            red[ridx(6 + p, rb, i, lane)] += aNH[rb][i];
          }
      }
      __syncthreads();

      {
        // R9-VERBATIM epilogue: wave w finishes rows [16w,16w+16).
#pragma unroll
        for (int i = 0; i < 4; ++i) {
          const int b = wave * 16 + kg * 4 + i;
          const float R  = red[ridx(0, wave, i, lane)] + red[ridx(1, wave, i, lane)];
          const float Z  = red[ridx(2, wave, i, lane)] + red[ridx(3, wave, i, lane)];
          const float NX = red[ridx(4, wave, i, lane)] + red[ridx(5, wave, i, lane)];
          const float NH = red[ridx(6, wave, i, lane)] + red[ridx(7, wave, i, lane)];
          const float r = sigmoid_f(R + bir + bhr);
          const float zz = sigmoid_f(Z + biz + bhz);
          const float nn = tanh_f(NX + bin_ + r * (NH + bhn));
          const float hp = h32l[(size_t)b * H_ + j];
          const float hnew = (1.0f - zz) * nn + zz * hp;
          h32l[(size_t)b * H_ + j] = hnew;
          ho[(size_t)b * H_ + j] = (f16)hnew;
        }
      }
    }
    light_barrier(a.flags, u + 1);
  }
}

__global__ void __launch_bounds__(NTHR, 1) gru_pipeline(Args a) {
  __shared__ float red[8 * 4 * 4 * 64];   // 32 KiB scalar f32 (R9-verified)

  const int tid = threadIdx.x;
  const int gtid = blockIdx.x * NTHR + tid;
  const int NT = NWG * NTHR;

  // ================= Phase 0: prologue (R6/R9 verbatim) ===================
  {
    const int nf4 = B_ * T_ * IN0_ / 4;
    for (int i = gtid; i < nf4; i += NT) {
      int k4 = i & 127;
      int q = i >> 7;
      int b = q & 63;
      int t = q >> 6;
      const float4 v = *(const float4*)(a.x + ((size_t)b * T_ + t) * IN0_ + k4 * 4);
      f16x4 o;
      o[0] = (f16)v.x; o[1] = (f16)v.y; o[2] = (f16)v.z; o[3] = (f16)v.w;
      *(f16x4*)(a.x16 + (size_t)i * 4) = o;
    }
  }
  {
    f16x8 z8 = {0, 0, 0, 0, 0, 0, 0, 0};
    for (int i = gtid; i < 4 * 2 * B_ * H_ / 8; i += NT)
      ((f16x8*)a.houts)[i] = z8;
    f32x4 z4 = {0, 0, 0, 0};
    for (int i = gtid; i < 4 * B_ * H_ / 4; i += NT)
      ((f32x4*)a.h32)[i] = z4;
  }
  for (int l = 0; l < 4; ++l) {
    const int In = l ? H_ : IN0_;
    const int K = In + H_;
    const int NKB = K / 32;
    const float* Wih = a.Wih[l];
    const float* Whh = a.Whh[l];
    f16* wp = a.wpack + WOFF_[l];
    const int nunits = 3 * H_ * K / 8;
    for (int uu = gtid; uu < nunits; uu += NT) {
      int lane = uu & 63;
      int q = uu >> 6;
      int kb = q % NKB; q /= NKB;
      int gate = q % 3;
      int subb = q / 3;
      int j = subb * 16 + (lane & 15);
      int g = gate * H_ + j;
      int k = kb * 32 + (lane >> 4) * 8;
      const float* src = (k < In) ? (Wih + (size_t)g * In + k)
                                  : (Whh + (size_t)g * H_ + (k - In));
      f16x8 vv;
#pragma unroll
      for (int e = 0; e < 8; ++e) vv[e] = (f16)src[e];
      ((f16x8*)wp)[uu] = vv;
    }
  }

  heavy_barrier(a.bar);   // full flush+invalidate once: x16/wpack now stable

  // ================= Phase 1: pipelined recurrence ========================
  const int wg = blockIdx.x;
  const int layer = wg >> 6;
  const int sub = wg & 63;

  if (layer == 0) run_layer<IN0_, false>(a, layer, sub, red);
  else            run_layer<H_, true>(a, layer, sub, red);

  heavy_barrier(a.bar);   // full visibility for h32 before FC

  // ================= Phase 2: final FC (R6/R9 verbatim) ==================
  for (int o = gtid; o < B_ * C_; o += NT) {
    const int b = o / C_;
    const int c = o - b * C_;
    const float* hv = a.h32 + (size_t)3 * B_ * H_ + (size_t)b * H_;
    const float* wv = a.fcw + (size_t)c * H_;
    float s = a.fcb[c];
    for (int k = 0; k < H_; k += 4) {
      const float4 h4 = *(const float4*)(hv + k);
      const float4 w4 = *(const float4*)(wv + k);
      s = fmaf(h4.x, w4.x, s);
      s = fmaf(h4.y, w4.y, s);
      s = fmaf(h4.z, w4.z, s);
      s = fmaf(h4.w, w4.w, s);
    }
    a.out[o] = s;
  }
}

extern "C" void kernel_launch(void* const* d_in, const int* in_sizes, int n_in,
                              void* d_out, int out_size, void* d_ws, size_t ws_size,
                              hipStream_t stream) {
  Args a;
  a.x = (const float*)d_in[0];
  for (int l = 0; l < 4; ++l) {
    a.Wih[l] = (const float*)d_in[1 + 4 * l];
    a.Whh[l] = (const float*)d_in[2 + 4 * l];
    a.bih[l] = (const float*)d_in[3 + 4 * l];
    a.bhh[l] = (const float*)d_in[4 + 4 * l];
  }
  a.fcw = (const float*)d_in[17];
  a.fcb = (const float*)d_in[18];
  a.out = (float*)d_out;

  char* ws = (char*)d_ws;
  size_t off = 0;
  a.wpack = (f16*)(ws + off); off += 23592960ul * 2;                  // 45 MiB
  a.x16   = (f16*)(ws + off); off += 16777216ul * 2;                  // 32 MiB
  a.houts = (f16*)(ws + off); off += 4ul * 2 * B_ * H_ * 2;           // 1 MiB
  a.h32   = (float*)(ws + off); off += 4ul * B_ * H_ * 4;             // 1 MiB
  a.flags = (int*)(ws + off); off += (NWG * 32 + 32) * sizeof(int);   // 33 KiB
  a.bar   = (int*)(ws + off); off += 256;

  hipMemsetAsync(a.flags, 0, (NWG * 32 + 32) * sizeof(int) + 256, stream);

  void* params[] = { &a };
  hipError_t err = hipLaunchCooperativeKernel((void*)gru_pipeline, dim3(NWG),
                                              dim3(NTHR), params, 0, stream);
  if (err != hipSuccess) {
    gru_pipeline<<<dim3(NWG), dim3(NTHR), 0, stream>>>(a);
  }
}

// Round 12
// 13068.848 us; speedup vs baseline: 3.9726x; 1.8633x over previous
//
#include <hip/hip_runtime.h>

#define B_ 64
#define T_ 512
#define IN0_ 512
#define H_ 1024
#define C_ 1000
#define NWG 256
#define NTHR 256

typedef _Float16 f16;
typedef _Float16 f16x8 __attribute__((ext_vector_type(8)));
typedef _Float16 f16x4 __attribute__((ext_vector_type(4)));
typedef float f32x4 __attribute__((ext_vector_type(4)));

struct Args {
  const float* x;
  const float* Wih[4];
  const float* Whh[4];
  const float* bih[4];
  const float* bhh[4];
  const float* fcw;
  const float* fcb;
  float* out;
  f16* wpack;
  f16* x16;     // [T][B][512] f16
  f16* houts;   // [4 layers][2 parity][64][1024] f16
  float* h32;   // [4 layers][64][1024] f32 master hidden (self RMW, L1-local)
  int* flags;   // NWG padded flags; flags[NWG*32] = go word (light barrier)
  int* bar;     // [0]=count, [1]=generation (heavy barrier)
};

__device__ __forceinline__ float sigmoid_f(float x) {
  return 1.0f / (1.0f + __expf(-x));
}
__device__ __forceinline__ float tanh_f(float x) {
  return 1.0f - 2.0f / (__expf(2.0f * x) + 1.0f);
}

// HEAVY barrier — R1 VERBATIM (HW-verified). Used twice only.
__device__ __forceinline__ void heavy_barrier(int* bar) {
  __threadfence();
  __syncthreads();
  if (threadIdx.x == 0) {
    int* cnt = bar;
    int* gen = bar + 1;
    int g = __hip_atomic_load(gen, __ATOMIC_RELAXED, __HIP_MEMORY_SCOPE_AGENT);
    int v = __hip_atomic_fetch_add(cnt, 1, __ATOMIC_ACQ_REL, __HIP_MEMORY_SCOPE_AGENT);
    if (v == NWG - 1) {
      __hip_atomic_store(cnt, 0, __ATOMIC_RELAXED, __HIP_MEMORY_SCOPE_AGENT);
      __hip_atomic_store(gen, g + 1, __ATOMIC_RELEASE, __HIP_MEMORY_SCOPE_AGENT);
    } else {
      int cur;
      do {
        __builtin_amdgcn_s_sleep(2);
        cur = __hip_atomic_load(gen, __ATOMIC_ACQUIRE, __HIP_MEMORY_SCOPE_AGENT);
      } while (cur == g);
    }
  }
  __syncthreads();
  __threadfence();
}

// LIGHT per-step barrier v2 — NO wbl2, NO invalidate. Shared data is written
// with agent-scope (sc1, write-through-to-L3) atomic stores in the epilogue;
// s_waitcnt vmcnt(0) in EVERY thread guarantees those stores completed at the
// coherent point before the WG's flag is raised. Consumers read via aload16
// (sc1, served at L3) — no cache maintenance needed anywhere in the loop.
__device__ __forceinline__ void light_barrier(int* flags, int step) {
  int* go = flags + NWG * 32;
  asm volatile("s_waitcnt vmcnt(0) lgkmcnt(0)" ::: "memory");
  __syncthreads();
  if (blockIdx.x == 0) {
    const int t = threadIdx.x;
    if (t > 0 && t < NWG) {
      while (__hip_atomic_load(flags + t * 32, __ATOMIC_RELAXED,
                               __HIP_MEMORY_SCOPE_AGENT) < step)
        __builtin_amdgcn_s_sleep(1);
    }
    __syncthreads();
    if (t == 0)
      __hip_atomic_store(go, step, __ATOMIC_RELAXED, __HIP_MEMORY_SCOPE_AGENT);
  } else {
    if (threadIdx.x == 0) {
      __hip_atomic_store(flags + blockIdx.x * 32, step, __ATOMIC_RELAXED,
                         __HIP_MEMORY_SCOPE_AGENT);
      while (__hip_atomic_load(go, __ATOMIC_RELAXED,
                               __HIP_MEMORY_SCOPE_AGENT) < step)
        __builtin_amdgcn_s_sleep(1);
    }
  }
  __syncthreads();
}

// Coherent 16B fragment load — R8/R10/R11 VERBATIM (HW-verified).
union U16B { unsigned long long u[2]; f16x8 v; };
__device__ __forceinline__ f16x8 aload16(const f16* p) {
  unsigned long long* q = (unsigned long long*)p;
  U16B r;
  r.u[0] = __hip_atomic_load(q,     __ATOMIC_RELAXED, __HIP_MEMORY_SCOPE_AGENT);
  r.u[1] = __hip_atomic_load(q + 1, __ATOMIC_RELAXED, __HIP_MEMORY_SCOPE_AGENT);
  return r.v;
}

// Coherent f16 store: agent-scope relaxed atomic store of the bit pattern
// (sc1 -> write-through to the memory-side coherent L3, no dirty L2 line).
union UF16 { f16 f; unsigned short u; };
__device__ __forceinline__ void astore2(f16* p, f16 v) {
  UF16 c; c.f = v;
  __hip_atomic_store((unsigned short*)p, c.u, __ATOMIC_RELAXED,
                     __HIP_MEMORY_SCOPE_AGENT);
}

// Packed-weight layer offsets in f16 elements (R6-verified repack layout).
__constant__ __device__ const size_t WOFF_[4] = {0ul, 4718592ul, 11010048ul, 17301504ul};

// LDS reduction slot (R9-verified scalar layout; banks R:0/1 Z:2/3 NX:4/5 NH:6/7).
__device__ __forceinline__ int ridx(int bank, int rb, int i, int lane) {
  return ((bank * 4 + rb) * 4 + i) * 64 + lane;
}

// R11-VERIFIED K-slice split layer. Only change: epilogue ho stores via
// astore2 (sc1), enabling the fence-free light barrier.
template <int IN, bool XA>
__device__ void run_layer(const Args& a, int layer, int sub, float* red) {
  constexpr int NKB = (IN + H_) / 32;   // 48 (layer0) or 64
  constexpr int NXB = IN / 32;          // 16 or 32
  constexpr int SLICE = NKB / 4;        // 12 or 16

  const int tid = threadIdx.x;
  const int wave = tid >> 6;            // 0..3
  const int lane = tid & 63;
  const int jc = lane & 15;
  const int kg = lane >> 4;
  const int j = sub * 16 + jc;
  const int wbase = wave * SLICE;

  const float bir = a.bih[layer][j], bhr = a.bhh[layer][j];
  const float biz = a.bih[layer][H_ + j], bhz = a.bhh[layer][H_ + j];
  const float bin_ = a.bih[layer][2 * H_ + j], bhn = a.bhh[layer][2 * H_ + j];

  // ---- gather this wave's K-slice weights, all 3 gates (R11-verified) ----
  const f16x8* wpb = (const f16x8*)(a.wpack + WOFF_[layer] +
                                    (size_t)sub * 3 * NKB * 512) + lane;
  f16x8 wfR[SLICE], wfZ[SLICE], wfN[SLICE];
#pragma unroll
  for (int kk = 0; kk < SLICE; ++kk) {
    wfR[kk] = wpb[(size_t)(0 * NKB + wbase + kk) * 64];
    wfZ[kk] = wpb[(size_t)(1 * NKB + wbase + kk) * 64];
    wfN[kk] = wpb[(size_t)(2 * NKB + wbase + kk) * 64];
  }

  f16* hout0 = a.houts + (size_t)(layer * 2 + 0) * B_ * H_;
  f16* hout1 = hout0 + B_ * H_;
  const f16* xp0 = layer ? a.houts + (size_t)((layer - 1) * 2) * B_ * H_ : (const f16*)nullptr;
  const f16* xp1 = layer ? xp0 + B_ * H_ : (const f16*)nullptr;
  float* h32l = a.h32 + (size_t)layer * B_ * H_;

  for (int u = 0; u < T_ + 3; ++u) {
    const int t = u - layer;
    if (t >= 0 && t < T_) {
      const f16* xbase = (IN == IN0_) ? (a.x16 + (size_t)t * B_ * IN0_)
                                      : ((t & 1) ? xp1 : xp0);
      const f16* hbase = ((t + 1) & 1) ? hout1 : hout0;
      f16* ho = (t & 1) ? hout1 : hout0;

      f32x4 aR[4], aZ[4], aNX[4], aNH[4];
#pragma unroll
      for (int rb = 0; rb < 4; ++rb) {
        aR[rb] = 0.f; aZ[rb] = 0.f; aNX[rb] = 0.f; aNH[rb] = 0.f;
      }

#pragma unroll
      for (int rb = 0; rb < 4; ++rb) {
        const int arow = rb * 16 + jc;
        const f16* xrow = xbase + (size_t)arow * IN + kg * 8;
        const f16* hrow = hbase + (size_t)arow * H_ + kg * 8;
#pragma unroll
        for (int kk = 0; kk < SLICE; ++kk) {
          const int kb = wbase + kk;
          const bool isx = kb < NXB;     // wave-uniform select (R9-verified)
          f16x8 af;
          if (isx) {
            if constexpr (XA) af = aload16(xrow + kb * 32);
            else              af = *(const f16x8*)(xrow + kb * 32);
          } else {
            af = aload16(hrow + (kb - NXB) * 32);
          }
          aR[rb] = __builtin_amdgcn_mfma_f32_16x16x32_f16(af, wfR[kk], aR[rb], 0, 0, 0);
          aZ[rb] = __builtin_amdgcn_mfma_f32_16x16x32_f16(af, wfZ[kk], aZ[rb], 0, 0, 0);
          const f16x8 z8 = {0, 0, 0, 0, 0, 0, 0, 0};
          const f16x8 afx = isx ? af : z8;   // masked N split (R9-verified)
          const f16x8 afh = isx ? z8 : af;
          aNX[rb] = __builtin_amdgcn_mfma_f32_16x16x32_f16(afx, wfN[kk], aNX[rb], 0, 0, 0);
          aNH[rb] = __builtin_amdgcn_mfma_f32_16x16x32_f16(afh, wfN[kk], aNH[rb], 0, 0, 0);
        }
      }

      // ---- two-phase scalar-LDS reduction (R11-verified) ----
      if (wave < 2) {                    // phase A: waves 0,1 write pair=wave
#pragma unroll
        for (int rb = 0; rb < 4; ++rb)
#pragma unroll
          for (int i = 0; i < 4; ++i) {
            red[ridx(0 + wave, rb, i, lane)] = aR[rb][i];
            red[ridx(2 + wave, rb, i, lane)] = aZ[rb][i];
            red[ridx(4 + wave, rb, i, lane)] = aNX[rb][i];
            red[ridx(6 + wave, rb, i, lane)] = aNH[rb][i];
          }
      }
      __syncthreads();
      if (wave >= 2) {                   // phase B: waves 2,3 add into pair=wave-2
        const int p = wave - 2;
#pragma unroll
        for (int rb = 0; rb < 4; ++rb)
#pragma unroll
          for (int i = 0; i < 4; ++i) {
            red[ridx(0 + p, rb, i, lane)] += aR[rb][i];
            red[ridx(2 + p, rb, i, lane)] += aZ[rb][i];
            red[ridx(4 + p, rb, i, lane)] += aNX[rb][i];
            red[ridx(6 + p, rb, i, lane)] += aNH[rb][i];
          }
      }
      __syncthreads();

      {
        // R9/R11 epilogue; ho stores now agent-scope sc1 (astore2).
#pragma unroll
        for (int i = 0; i < 4; ++i) {
          const int b = wave * 16 + kg * 4 + i;
          const float R  = red[ridx(0, wave, i, lane)] + red[ridx(1, wave, i, lane)];
          const float Z  = red[ridx(2, wave, i, lane)] + red[ridx(3, wave, i, lane)];
          const float NX = red[ridx(4, wave, i, lane)] + red[ridx(5, wave, i, lane)];
          const float NH = red[ridx(6, wave, i, lane)] + red[ridx(7, wave, i, lane)];
          const float r = sigmoid_f(R + bir + bhr);
          const float zz = sigmoid_f(Z + biz + bhz);
          const float nn = tanh_f(NX + bin_ + r * (NH + bhn));
          const float hp = h32l[(size_t)b * H_ + j];
          const float hnew = (1.0f - zz) * nn + zz * hp;
          h32l[(size_t)b * H_ + j] = hnew;           // self-RMW, ordinary/cached
          astore2(&ho[(size_t)b * H_ + j], (f16)hnew);  // cross-WG, sc1 -> L3
        }
      }
    }
    light_barrier(a.flags, u + 1);
  }
}

__global__ void __launch_bounds__(NTHR, 1) gru_pipeline(Args a) {
  __shared__ float red[8 * 4 * 4 * 64];   // 32 KiB scalar f32 (R9-verified)

  const int tid = threadIdx.x;
  const int gtid = blockIdx.x * NTHR + tid;
  const int NT = NWG * NTHR;

  // ================= Phase 0: prologue (R6/R9/R11 verbatim) ===============
  {
    const int nf4 = B_ * T_ * IN0_ / 4;
    for (int i = gtid; i < nf4; i += NT) {
      int k4 = i & 127;
      int q = i >> 7;
      int b = q & 63;
      int t = q >> 6;
      const float4 v = *(const float4*)(a.x + ((size_t)b * T_ + t) * IN0_ + k4 * 4);
      f16x4 o;
      o[0] = (f16)v.x; o[1] = (f16)v.y; o[2] = (f16)v.z; o[3] = (f16)v.w;
      *(f16x4*)(a.x16 + (size_t)i * 4) = o;
    }
  }
  {
    f16x8 z8 = {0, 0, 0, 0, 0, 0, 0, 0};
    for (int i = gtid; i < 4 * 2 * B_ * H_ / 8; i += NT)
      ((f16x8*)a.houts)[i] = z8;
    f32x4 z4 = {0, 0, 0, 0};
    for (int i = gtid; i < 4 * B_ * H_ / 4; i += NT)
      ((f32x4*)a.h32)[i] = z4;
  }
  for (int l = 0; l < 4; ++l) {
    const int In = l ? H_ : IN0_;
    const int K = In + H_;
    const int NKB = K / 32;
    const float* Wih = a.Wih[l];
    const float* Whh = a.Whh[l];
    f16* wp = a.wpack + WOFF_[l];
    const int nunits = 3 * H_ * K / 8;
    for (int uu = gtid; uu < nunits; uu += NT) {
      int lane = uu & 63;
      int q = uu >> 6;
      int kb = q % NKB; q /= NKB;
      int gate = q % 3;
      int subb = q / 3;
      int j = subb * 16 + (lane & 15);
      int g = gate * H_ + j;
      int k = kb * 32 + (lane >> 4) * 8;
      const float* src = (k < In) ? (Wih + (size_t)g * In + k)
                                  : (Whh + (size_t)g * H_ + (k - In));
      f16x8 vv;
#pragma unroll
      for (int e = 0; e < 8; ++e) vv[e] = (f16)src[e];
      ((f16x8*)wp)[uu] = vv;
    }
  }

  heavy_barrier(a.bar);   // full flush+invalidate once: x16/wpack now stable

  // ================= Phase 1: pipelined recurrence ========================
  const int wg = blockIdx.x;
  const int layer = wg >> 6;
  const int sub = wg & 63;

  if (layer == 0) run_layer<IN0_, false>(a, layer, sub, red);
  else            run_layer<H_, true>(a, layer, sub, red);

  heavy_barrier(a.bar);   // full visibility for h32 before FC

  // ================= Phase 2: final FC (R6/R9/R11 verbatim) ==============
  for (int o = gtid; o < B_ * C_; o += NT) {
    const int b = o / C_;
    const int c = o - b * C_;
    const float* hv = a.h32 + (size_t)3 * B_ * H_ + (size_t)b * H_;
    const float* wv = a.fcw + (size_t)c * H_;
    float s = a.fcb[c];
    for (int k = 0; k < H_; k += 4) {
      const float4 h4 = *(const float4*)(hv + k);
      const float4 w4 = *(const float4*)(wv + k);
      s = fmaf(h4.x, w4.x, s);
      s = fmaf(h4.y, w4.y, s);
      s = fmaf(h4.z, w4.z, s);
      s = fmaf(h4.w, w4.w, s);
    }
    a.out[o] = s;
  }
}

extern "C" void kernel_launch(void* const* d_in, const int* in_sizes, int n_in,
                              void* d_out, int out_size, void* d_ws, size_t ws_size,
                              hipStream_t stream) {
  Args a;
  a.x = (const float*)d_in[0];
  for (int l = 0; l < 4; ++l) {
    a.Wih[l] = (const float*)d_in[1 + 4 * l];
    a.Whh[l] = (const float*)d_in[2 + 4 * l];
    a.bih[l] = (const float*)d_in[3 + 4 * l];
    a.bhh[l] = (const float*)d_in[4 + 4 * l];
  }
  a.fcw = (const float*)d_in[17];
  a.fcb = (const float*)d_in[18];
  a.out = (float*)d_out;

  char* ws = (char*)d_ws;
  size_t off = 0;
  a.wpack = (f16*)(ws + off); off += 23592960ul * 2;                  // 45 MiB
  a.x16   = (f16*)(ws + off); off += 16777216ul * 2;                  // 32 MiB
  a.houts = (f16*)(ws + off); off += 4ul * 2 * B_ * H_ * 2;           // 1 MiB
  a.h32   = (float*)(ws + off); off += 4ul * B_ * H_ * 4;             // 1 MiB
  a.flags = (int*)(ws + off); off += (NWG * 32 + 32) * sizeof(int);   // 33 KiB
  a.bar   = (int*)(ws + off); off += 256;

  hipMemsetAsync(a.flags, 0, (NWG * 32 + 32) * sizeof(int) + 256, stream);

  void* params[] = { &a };
  hipError_t err = hipLaunchCooperativeKernel((void*)gru_pipeline, dim3(NWG),
                                              dim3(NTHR), params, 0, stream);
  if (err != hipSuccess) {
    gru_pipeline<<<dim3(NWG), dim3(NTHR), 0, stream>>>(a);
  }
}

// Round 13
// 11567.340 us; speedup vs baseline: 4.4882x; 1.1298x over previous
//
#include <hip/hip_runtime.h>

#define B_ 64
#define T_ 512
#define IN0_ 512
#define H_ 1024
#define C_ 1000
#define NWG 256
#define NTHR 256

typedef _Float16 f16;
typedef _Float16 f16x8 __attribute__((ext_vector_type(8)));
typedef _Float16 f16x4 __attribute__((ext_vector_type(4)));
typedef float f32x4 __attribute__((ext_vector_type(4)));

struct Args {
  const float* x;
  const float* Wih[4];
  const float* Whh[4];
  const float* bih[4];
  const float* bhh[4];
  const float* fcw;
  const float* fcb;
  float* out;
  f16* wpack;
  f16* x16;     // [T][B][512] f16
  f16* houts;   // [4 layers][2 parity][64][1024] f16
  float* h32;   // [4 layers][64][1024] f32 master hidden (self RMW, L1-local)
  int* flags;   // NWG padded flags; flags[NWG*32] = go word (light barrier)
  int* bar;     // [0]=count, [1]=generation (heavy barrier)
};

__device__ __forceinline__ float sigmoid_f(float x) {
  return 1.0f / (1.0f + __expf(-x));
}
__device__ __forceinline__ float tanh_f(float x) {
  return 1.0f - 2.0f / (__expf(2.0f * x) + 1.0f);
}

// HEAVY barrier — R1 VERBATIM (HW-verified). Used twice only.
__device__ __forceinline__ void heavy_barrier(int* bar) {
  __threadfence();
  __syncthreads();
  if (threadIdx.x == 0) {
    int* cnt = bar;
    int* gen = bar + 1;
    int g = __hip_atomic_load(gen, __ATOMIC_RELAXED, __HIP_MEMORY_SCOPE_AGENT);
    int v = __hip_atomic_fetch_add(cnt, 1, __ATOMIC_ACQ_REL, __HIP_MEMORY_SCOPE_AGENT);
    if (v == NWG - 1) {
      __hip_atomic_store(cnt, 0, __ATOMIC_RELAXED, __HIP_MEMORY_SCOPE_AGENT);
      __hip_atomic_store(gen, g + 1, __ATOMIC_RELEASE, __HIP_MEMORY_SCOPE_AGENT);
    } else {
      int cur;
      do {
        __builtin_amdgcn_s_sleep(2);
        cur = __hip_atomic_load(gen, __ATOMIC_ACQUIRE, __HIP_MEMORY_SCOPE_AGENT);
      } while (cur == g);
    }
  }
  __syncthreads();
  __threadfence();
}

// LIGHT per-step barrier — R12 VERBATIM (HW-verified PASS). No wbl2, no
// invalidate: shared data moves via sc1 stores/loads at the coherent L3;
// vmcnt(0) in every thread orders data ahead of the flag.
__device__ __forceinline__ void light_barrier(int* flags, int step) {
  int* go = flags + NWG * 32;
  asm volatile("s_waitcnt vmcnt(0) lgkmcnt(0)" ::: "memory");
  __syncthreads();
  if (blockIdx.x == 0) {
    const int t = threadIdx.x;
    if (t > 0 && t < NWG) {
      while (__hip_atomic_load(flags + t * 32, __ATOMIC_RELAXED,
                               __HIP_MEMORY_SCOPE_AGENT) < step)
        __builtin_amdgcn_s_sleep(1);
    }
    __syncthreads();
    if (t == 0)
      __hip_atomic_store(go, step, __ATOMIC_RELAXED, __HIP_MEMORY_SCOPE_AGENT);
  } else {
    if (threadIdx.x == 0) {
      __hip_atomic_store(flags + blockIdx.x * 32, step, __ATOMIC_RELAXED,
                         __HIP_MEMORY_SCOPE_AGENT);
      while (__hip_atomic_load(go, __ATOMIC_RELAXED,
                               __HIP_MEMORY_SCOPE_AGENT) < step)
        __builtin_amdgcn_s_sleep(1);
    }
  }
  __syncthreads();
}

// Coherent 16B fragment load — R8/R10/R11/R12 VERBATIM (HW-verified).
union U16B { unsigned long long u[2]; f16x8 v; };
__device__ __forceinline__ f16x8 aload16(const f16* p) {
  unsigned long long* q = (unsigned long long*)p;
  U16B r;
  r.u[0] = __hip_atomic_load(q,     __ATOMIC_RELAXED, __HIP_MEMORY_SCOPE_AGENT);
  r.u[1] = __hip_atomic_load(q + 1, __ATOMIC_RELAXED, __HIP_MEMORY_SCOPE_AGENT);
  return r.v;
}

// Coherent f16 store — R12 VERBATIM (sc1, write-through to L3).
union UF16 { f16 f; unsigned short u; };
__device__ __forceinline__ void astore2(f16* p, f16 v) {
  UF16 c; c.f = v;
  __hip_atomic_store((unsigned short*)p, c.u, __ATOMIC_RELAXED,
                     __HIP_MEMORY_SCOPE_AGENT);
}

// Packed-weight layer offsets in f16 elements (R6-verified repack layout).
__constant__ __device__ const size_t WOFF_[4] = {0ul, 4718592ul, 11010048ul, 17301504ul};

// LDS reduction slot (R9-verified scalar layout; banks R:0/1 Z:2/3 NX:4/5 NH:6/7).
__device__ __forceinline__ int ridx(int bank, int rb, int i, int lane) {
  return ((bank * 4 + rb) * 4 + i) * 64 + lane;
}

// R12-VERIFIED K-slice layer. Only change: the rb-loop is restructured into
// explicitly BATCHED, double-buffered loads (LOADRB issues all SLICE frags
// back-to-back; MFMARB consumes the previous batch) so the sc1/L3 load
// latency overlaps MFMA work instead of serializing. Arithmetic identical.
template <int IN, bool XA>
__device__ void run_layer(const Args& a, int layer, int sub, float* red) {
  constexpr int NKB = (IN + H_) / 32;   // 48 (layer0) or 64
  constexpr int NXB = IN / 32;          // 16 or 32
  constexpr int SLICE = NKB / 4;        // 12 or 16

  const int tid = threadIdx.x;
  const int wave = tid >> 6;            // 0..3
  const int lane = tid & 63;
  const int jc = lane & 15;
  const int kg = lane >> 4;
  const int j = sub * 16 + jc;
  const int wbase = wave * SLICE;

  const float bir = a.bih[layer][j], bhr = a.bhh[layer][j];
  const float biz = a.bih[layer][H_ + j], bhz = a.bhh[layer][H_ + j];
  const float bin_ = a.bih[layer][2 * H_ + j], bhn = a.bhh[layer][2 * H_ + j];

  // ---- gather this wave's K-slice weights, all 3 gates (R11-verified) ----
  const f16x8* wpb = (const f16x8*)(a.wpack + WOFF_[layer] +
                                    (size_t)sub * 3 * NKB * 512) + lane;
  f16x8 wfR[SLICE], wfZ[SLICE], wfN[SLICE];
#pragma unroll
  for (int kk = 0; kk < SLICE; ++kk) {
    wfR[kk] = wpb[(size_t)(0 * NKB + wbase + kk) * 64];
    wfZ[kk] = wpb[(size_t)(1 * NKB + wbase + kk) * 64];
    wfN[kk] = wpb[(size_t)(2 * NKB + wbase + kk) * 64];
  }

  f16* hout0 = a.houts + (size_t)(layer * 2 + 0) * B_ * H_;
  f16* hout1 = hout0 + B_ * H_;
  const f16* xp0 = layer ? a.houts + (size_t)((layer - 1) * 2) * B_ * H_ : (const f16*)nullptr;
  const f16* xp1 = layer ? xp0 + B_ * H_ : (const f16*)nullptr;
  float* h32l = a.h32 + (size_t)layer * B_ * H_;

  for (int u = 0; u < T_ + 3; ++u) {
    const int t = u - layer;
    if (t >= 0 && t < T_) {
      const f16* xbase = (IN == IN0_) ? (a.x16 + (size_t)t * B_ * IN0_)
                                      : ((t & 1) ? xp1 : xp0);
      const f16* hbase = ((t + 1) & 1) ? hout1 : hout0;
      f16* ho = (t & 1) ? hout1 : hout0;

      f32x4 aR[4], aZ[4], aNX[4], aNH[4];
#pragma unroll
      for (int rb = 0; rb < 4; ++rb) {
        aR[rb] = 0.f; aZ[rb] = 0.f; aNX[rb] = 0.f; aNH[rb] = 0.f;
      }

// Issue ALL SLICE fragment loads for row-block RB back-to-back (no consumer
// between issues -> no intervening waitcnt; atomics keep program order).
#define LOADRB(BUF, RB)                                                      \
  do {                                                                       \
    const int arow_ = (RB) * 16 + jc;                                        \
    const f16* xrow_ = xbase + (size_t)arow_ * IN + kg * 8;                  \
    const f16* hrow_ = hbase + (size_t)arow_ * H_ + kg * 8;                  \
    _Pragma("unroll")                                                        \
    for (int kk = 0; kk < SLICE; ++kk) {                                     \
      const int kb_ = wbase + kk;                                            \
      if (kb_ < NXB) {                                                       \
        if constexpr (XA) BUF[kk] = aload16(xrow_ + kb_ * 32);               \
        else              BUF[kk] = *(const f16x8*)(xrow_ + kb_ * 32);       \
      } else {                                                               \
        BUF[kk] = aload16(hrow_ + (kb_ - NXB) * 32);                         \
      }                                                                      \
    }                                                                        \
  } while (0)

// Consume a batch: R9/R12-verified arithmetic, same accumulation order.
#define MFMARB(BUF, RB)                                                      \
  do {                                                                       \
    _Pragma("unroll")                                                        \
    for (int kk = 0; kk < SLICE; ++kk) {                                     \
      const int kb_ = wbase + kk;                                            \
      const bool isx_ = kb_ < NXB;                                           \
      const f16x8 af_ = BUF[kk];                                             \
      aR[RB] = __builtin_amdgcn_mfma_f32_16x16x32_f16(af_, wfR[kk], aR[RB], 0, 0, 0); \
      aZ[RB] = __builtin_amdgcn_mfma_f32_16x16x32_f16(af_, wfZ[kk], aZ[RB], 0, 0, 0); \
      const f16x8 z8_ = {0, 0, 0, 0, 0, 0, 0, 0};                            \
      const f16x8 afx_ = isx_ ? af_ : z8_;                                   \
      const f16x8 afh_ = isx_ ? z8_ : af_;                                   \
      aNX[RB] = __builtin_amdgcn_mfma_f32_16x16x32_f16(afx_, wfN[kk], aNX[RB], 0, 0, 0); \
      aNH[RB] = __builtin_amdgcn_mfma_f32_16x16x32_f16(afh_, wfN[kk], aNH[RB], 0, 0, 0); \
    }                                                                        \
  } while (0)

      {
        f16x8 bufA[SLICE], bufB[SLICE];
        LOADRB(bufA, 0);        // rb0 in flight
        LOADRB(bufB, 1);        // rb1 in flight (2-deep)
        MFMARB(bufA, 0);        // compute rb0 while rb1 lands
        LOADRB(bufA, 2);        // rb2 in flight
        MFMARB(bufB, 1);
        LOADRB(bufB, 3);        // rb3 in flight
        MFMARB(bufA, 2);
        MFMARB(bufB, 3);
      }
#undef LOADRB
#undef MFMARB

      // ---- two-phase scalar-LDS reduction (R11/R12-verified) ----
      if (wave < 2) {                    // phase A: waves 0,1 write pair=wave
#pragma unroll
        for (int rb = 0; rb < 4; ++rb)
#pragma unroll
          for (int i = 0; i < 4; ++i) {
            red[ridx(0 + wave, rb, i, lane)] = aR[rb][i];
            red[ridx(2 + wave, rb, i, lane)] = aZ[rb][i];
            red[ridx(4 + wave, rb, i, lane)] = aNX[rb][i];
            red[ridx(6 + wave, rb, i, lane)] = aNH[rb][i];
          }
      }
      __syncthreads();
      if (wave >= 2) {                   // phase B: waves 2,3 add into pair=wave-2
        const int p = wave - 2;
#pragma unroll
        for (int rb = 0; rb < 4; ++rb)
#pragma unroll
          for (int i = 0; i < 4; ++i) {
            red[ridx(0 + p, rb, i, lane)] += aR[rb][i];
            red[ridx(2 + p, rb, i, lane)] += aZ[rb][i];
            red[ridx(4 + p, rb, i, lane)] += aNX[rb][i];
            red[ridx(6 + p, rb, i, lane)] += aNH[rb][i];
          }
      }
      __syncthreads();

      {
        // R9/R12 epilogue; ho stores agent-scope sc1 (astore2).
#pragma unroll
        for (int i = 0; i < 4; ++i) {
          const int b = wave * 16 + kg * 4 + i;
          const float R  = red[ridx(0, wave, i, lane)] + red[ridx(1, wave, i, lane)];
          const float Z  = red[ridx(2, wave, i, lane)] + red[ridx(3, wave, i, lane)];
          const float NX = red[ridx(4, wave, i, lane)] + red[ridx(5, wave, i, lane)];
          const float NH = red[ridx(6, wave, i, lane)] + red[ridx(7, wave, i, lane)];
          const float r = sigmoid_f(R + bir + bhr);
          const float zz = sigmoid_f(Z + biz + bhz);
          const float nn = tanh_f(NX + bin_ + r * (NH + bhn));
          const float hp = h32l[(size_t)b * H_ + j];
          const float hnew = (1.0f - zz) * nn + zz * hp;
          h32l[(size_t)b * H_ + j] = hnew;             // self-RMW, cached
          astore2(&ho[(size_t)b * H_ + j], (f16)hnew); // cross-WG, sc1 -> L3
        }
      }
    }
    light_barrier(a.flags, u + 1);
  }
}

__global__ void __launch_bounds__(NTHR, 1) gru_pipeline(Args a) {
  __shared__ float red[8 * 4 * 4 * 64];   // 32 KiB scalar f32 (R9-verified)

  const int tid = threadIdx.x;
  const int gtid = blockIdx.x * NTHR + tid;
  const int NT = NWG * NTHR;

  // ================= Phase 0: prologue (R6/R9/R11/R12 verbatim) ===========
  {
    const int nf4 = B_ * T_ * IN0_ / 4;
    for (int i = gtid; i < nf4; i += NT) {
      int k4 = i & 127;
      int q = i >> 7;
      int b = q & 63;
      int t = q >> 6;
      const float4 v = *(const float4*)(a.x + ((size_t)b * T_ + t) * IN0_ + k4 * 4);
      f16x4 o;
      o[0] = (f16)v.x; o[1] = (f16)v.y; o[2] = (f16)v.z; o[3] = (f16)v.w;
      *(f16x4*)(a.x16 + (size_t)i * 4) = o;
    }
  }
  {
    f16x8 z8 = {0, 0, 0, 0, 0, 0, 0, 0};
    for (int i = gtid; i < 4 * 2 * B_ * H_ / 8; i += NT)
      ((f16x8*)a.houts)[i] = z8;
    f32x4 z4 = {0, 0, 0, 0};
    for (int i = gtid; i < 4 * B_ * H_ / 4; i += NT)
      ((f32x4*)a.h32)[i] = z4;
  }
  for (int l = 0; l < 4; ++l) {
    const int In = l ? H_ : IN0_;
    const int K = In + H_;
    const int NKB = K / 32;
    const float* Wih = a.Wih[l];
    const float* Whh = a.Whh[l];
    f16* wp = a.wpack + WOFF_[l];
    const int nunits = 3 * H_ * K / 8;
    for (int uu = gtid; uu < nunits; uu += NT) {
      int lane = uu & 63;
      int q = uu >> 6;
      int kb = q % NKB; q /= NKB;
      int gate = q % 3;
      int subb = q / 3;
      int j = subb * 16 + (lane & 15);
      int g = gate * H_ + j;
      int k = kb * 32 + (lane >> 4) * 8;
      const float* src = (k < In) ? (Wih + (size_t)g * In + k)
                                  : (Whh + (size_t)g * H_ + (k - In));
      f16x8 vv;
#pragma unroll
      for (int e = 0; e < 8; ++e) vv[e] = (f16)src[e];
      ((f16x8*)wp)[uu] = vv;
    }
  }

  heavy_barrier(a.bar);   // full flush+invalidate once: x16/wpack now stable

  // ================= Phase 1: pipelined recurrence ========================
  const int wg = blockIdx.x;
  const int layer = wg >> 6;
  const int sub = wg & 63;

  if (layer == 0) run_layer<IN0_, false>(a, layer, sub, red);
  else            run_layer<H_, true>(a, layer, sub, red);

  heavy_barrier(a.bar);   // full visibility for h32 before FC

  // ================= Phase 2: final FC (verbatim) ========================
  for (int o = gtid; o < B_ * C_; o += NT) {
    const int b = o / C_;
    const int c = o - b * C_;
    const float* hv = a.h32 + (size_t)3 * B_ * H_ + (size_t)b * H_;
    const float* wv = a.fcw + (size_t)c * H_;
    float s = a.fcb[c];
    for (int k = 0; k < H_; k += 4) {
      const float4 h4 = *(const float4*)(hv + k);
      const float4 w4 = *(const float4*)(wv + k);
      s = fmaf(h4.x, w4.x, s);
      s = fmaf(h4.y, w4.y, s);
      s = fmaf(h4.z, w4.z, s);
      s = fmaf(h4.w, w4.w, s);
    }
    a.out[o] = s;
  }
}

extern "C" void kernel_launch(void* const* d_in, const int* in_sizes, int n_in,
                              void* d_out, int out_size, void* d_ws, size_t ws_size,
                              hipStream_t stream) {
  Args a;
  a.x = (const float*)d_in[0];
  for (int l = 0; l < 4; ++l) {
    a.Wih[l] = (const float*)d_in[1 + 4 * l];
    a.Whh[l] = (const float*)d_in[2 + 4 * l];
    a.bih[l] = (const float*)d_in[3 + 4 * l];
    a.bhh[l] = (const float*)d_in[4 + 4 * l];
  }
  a.fcw = (const float*)d_in[17];
  a.fcb = (const float*)d_in[18];
  a.out = (float*)d_out;

  char* ws = (char*)d_ws;
  size_t off = 0;
  a.wpack = (f16*)(ws + off); off += 23592960ul * 2;                  // 45 MiB
  a.x16   = (f16*)(ws + off); off += 16777216ul * 2;                  // 32 MiB
  a.houts = (f16*)(ws + off); off += 4ul * 2 * B_ * H_ * 2;           // 1 MiB
  a.h32   = (float*)(ws + off); off += 4ul * B_ * H_ * 4;             // 1 MiB
  a.flags = (int*)(ws + off); off += (NWG * 32 + 32) * sizeof(int);   // 33 KiB
  a.bar   = (int*)(ws + off); off += 256;

  hipMemsetAsync(a.flags, 0, (NWG * 32 + 32) * sizeof(int) + 256, stream);

  void* params[] = { &a };
  hipError_t err = hipLaunchCooperativeKernel((void*)gru_pipeline, dim3(NWG),
                                              dim3(NTHR), params, 0, stream);
  if (err != hipSuccess) {
    gru_pipeline<<<dim3(NWG), dim3(NTHR), 0, stream>>>(a);
  }
}

// Round 14
// 11554.804 us; speedup vs baseline: 4.4931x; 1.0011x over previous
//
#include <hip/hip_runtime.h>

#define B_ 64
#define T_ 512
#define IN0_ 512
#define H_ 1024
#define C_ 1000
#define NWG 256
#define NTHR 256

typedef _Float16 f16;
typedef _Float16 f16x8 __attribute__((ext_vector_type(8)));
typedef _Float16 f16x4 __attribute__((ext_vector_type(4)));
typedef float f32x4 __attribute__((ext_vector_type(4)));

struct Args {
  const float* x;
  const float* Wih[4];
  const float* Whh[4];
  const float* bih[4];
  const float* bhh[4];
  const float* fcw;
  const float* fcb;
  float* out;
  f16* wpack;
  f16* x16;     // [T][B][512] f16
  f16* houts;   // [4 layers][2 parity][64][1024] f16 (sc1-written)
  float* h32f;  // [64][1024] f32 final hidden of layer 3 (sc1-written)
  int* flags;   // NWG padded flags; flags[NWG*32] = go word (light barrier)
  int* bar;     // [0]=count, [1]=generation (heavy barrier)
};

__device__ __forceinline__ float sigmoid_f(float x) {
  return 1.0f / (1.0f + __expf(-x));
}
__device__ __forceinline__ float tanh_f(float x) {
  return 1.0f - 2.0f / (__expf(2.0f * x) + 1.0f);
}

// HEAVY barrier — R1 VERBATIM (HW-verified). Used twice only.
__device__ __forceinline__ void heavy_barrier(int* bar) {
  __threadfence();
  __syncthreads();
  if (threadIdx.x == 0) {
    int* cnt = bar;
    int* gen = bar + 1;
    int g = __hip_atomic_load(gen, __ATOMIC_RELAXED, __HIP_MEMORY_SCOPE_AGENT);
    int v = __hip_atomic_fetch_add(cnt, 1, __ATOMIC_ACQ_REL, __HIP_MEMORY_SCOPE_AGENT);
    if (v == NWG - 1) {
      __hip_atomic_store(cnt, 0, __ATOMIC_RELAXED, __HIP_MEMORY_SCOPE_AGENT);
      __hip_atomic_store(gen, g + 1, __ATOMIC_RELEASE, __HIP_MEMORY_SCOPE_AGENT);
    } else {
      int cur;
      do {
        __builtin_amdgcn_s_sleep(2);
        cur = __hip_atomic_load(gen, __ATOMIC_ACQUIRE, __HIP_MEMORY_SCOPE_AGENT);
      } while (cur == g);
    }
  }
  __syncthreads();
  __threadfence();
}

// LIGHT per-step barrier v3.
// Producer side (R12-verified): shared data written with sc1 stores;
// s_waitcnt vmcnt(0) in every thread orders data ahead of the flag.
// Consumer side (NEW): acquire fence (buffer_inv — flash invalidate, no
// writeback scan) after `go`, so ORDINARY cached loads see fresh L3 data
// and same-XCD WGs share activation lines through L2.
// SAFETY INVARIANT: no ordinary dirty global lines exist in the loop
// (h-master is in LDS; ho/h32f are sc1 write-through), so inv loses nothing.
__device__ __forceinline__ void light_barrier(int* flags, int step) {
  int* go = flags + NWG * 32;
  asm volatile("s_waitcnt vmcnt(0) lgkmcnt(0)" ::: "memory");
  __syncthreads();
  if (blockIdx.x == 0) {
    const int t = threadIdx.x;
    if (t > 0 && t < NWG) {
      while (__hip_atomic_load(flags + t * 32, __ATOMIC_RELAXED,
                               __HIP_MEMORY_SCOPE_AGENT) < step)
        __builtin_amdgcn_s_sleep(1);
    }
    __syncthreads();
    if (t == 0)
      __hip_atomic_store(go, step, __ATOMIC_RELAXED, __HIP_MEMORY_SCOPE_AGENT);
  } else {
    if (threadIdx.x == 0) {
      __hip_atomic_store(flags + blockIdx.x * 32, step, __ATOMIC_RELAXED,
                         __HIP_MEMORY_SCOPE_AGENT);
      while (__hip_atomic_load(go, __ATOMIC_RELAXED,
                               __HIP_MEMORY_SCOPE_AGENT) < step)
        __builtin_amdgcn_s_sleep(1);
    }
  }
  __syncthreads();
  __builtin_amdgcn_fence(__ATOMIC_ACQUIRE, "agent");   // inv stale L1/L2
}

// Coherent f16 store — R12 VERBATIM (sc1, write-through to L3).
union UF16 { f16 f; unsigned short u; };
__device__ __forceinline__ void astore2(f16* p, f16 v) {
  UF16 c; c.f = v;
  __hip_atomic_store((unsigned short*)p, c.u, __ATOMIC_RELAXED,
                     __HIP_MEMORY_SCOPE_AGENT);
}
union UF32 { float f; unsigned u; };
__device__ __forceinline__ void astore4(float* p, float v) {
  UF32 c; c.f = v;
  __hip_atomic_store((unsigned*)p, c.u, __ATOMIC_RELAXED,
                     __HIP_MEMORY_SCOPE_AGENT);
}

// Packed-weight layer offsets in f16 elements (R6-verified repack layout).
__constant__ __device__ const size_t WOFF_[4] = {0ul, 4718592ul, 11010048ul, 17301504ul};

// LDS reduction slot (R9-verified scalar layout; banks R:0/1 Z:2/3 NX:4/5 NH:6/7).
__device__ __forceinline__ int ridx(int bank, int rb, int i, int lane) {
  return ((bank * 4 + rb) * 4 + i) * 64 + lane;
}

// R13-VERIFIED K-slice layer. Changes: (1) ALL activation loads ordinary
// (L2-shareable; safe because per-step acquire-inv in light_barrier),
// (2) h-master in LDS (hlds, stride 17) instead of global RMW,
// (3) final h via sc1 f32 store to h32f.
template <int IN>
__device__ void run_layer(const Args& a, int layer, int sub, bool is_last,
                          float* red, float* hlds) {
  constexpr int NKB = (IN + H_) / 32;   // 48 (layer0) or 64
  constexpr int NXB = IN / 32;          // 16 or 32
  constexpr int SLICE = NKB / 4;        // 12 or 16

  const int tid = threadIdx.x;
  const int wave = tid >> 6;            // 0..3
  const int lane = tid & 63;
  const int jc = lane & 15;
  const int kg = lane >> 4;
  const int j = sub * 16 + jc;
  const int wbase = wave * SLICE;

  const float bir = a.bih[layer][j], bhr = a.bhh[layer][j];
  const float biz = a.bih[layer][H_ + j], bhz = a.bhh[layer][H_ + j];
  const float bin_ = a.bih[layer][2 * H_ + j], bhn = a.bhh[layer][2 * H_ + j];

  // ---- gather this wave's K-slice weights, all 3 gates (R11-verified) ----
  const f16x8* wpb = (const f16x8*)(a.wpack + WOFF_[layer] +
                                    (size_t)sub * 3 * NKB * 512) + lane;
  f16x8 wfR[SLICE], wfZ[SLICE], wfN[SLICE];
#pragma unroll
  for (int kk = 0; kk < SLICE; ++kk) {
    wfR[kk] = wpb[(size_t)(0 * NKB + wbase + kk) * 64];
    wfZ[kk] = wpb[(size_t)(1 * NKB + wbase + kk) * 64];
    wfN[kk] = wpb[(size_t)(2 * NKB + wbase + kk) * 64];
  }

  f16* hout0 = a.houts + (size_t)(layer * 2 + 0) * B_ * H_;
  f16* hout1 = hout0 + B_ * H_;
  const f16* xp0 = layer ? a.houts + (size_t)((layer - 1) * 2) * B_ * H_ : (const f16*)nullptr;
  const f16* xp1 = layer ? xp0 + B_ * H_ : (const f16*)nullptr;

  for (int u = 0; u < T_ + 3; ++u) {
    const int t = u - layer;
    if (t >= 0 && t < T_) {
      const f16* xbase = (IN == IN0_) ? (a.x16 + (size_t)t * B_ * IN0_)
                                      : ((t & 1) ? xp1 : xp0);
      const f16* hbase = ((t + 1) & 1) ? hout1 : hout0;
      f16* ho = (t & 1) ? hout1 : hout0;

      f32x4 aR[4], aZ[4], aNX[4], aNH[4];
#pragma unroll
      for (int rb = 0; rb < 4; ++rb) {
        aR[rb] = 0.f; aZ[rb] = 0.f; aNX[rb] = 0.f; aNH[rb] = 0.f;
      }

// Batched ordinary loads for row-block RB (compiler tracks vmcnt finely on
// non-atomic loads -> deep pipelining across the double buffer).
#define LOADRB(BUF, RB)                                                      \
  do {                                                                       \
    const int arow_ = (RB) * 16 + jc;                                        \
    const f16* xrow_ = xbase + (size_t)arow_ * IN + kg * 8;                  \
    const f16* hrow_ = hbase + (size_t)arow_ * H_ + kg * 8;                  \
    _Pragma("unroll")                                                        \
    for (int kk = 0; kk < SLICE; ++kk) {                                     \
      const int kb_ = wbase + kk;                                            \
      BUF[kk] = (kb_ < NXB) ? *(const f16x8*)(xrow_ + kb_ * 32)              \
                            : *(const f16x8*)(hrow_ + (kb_ - NXB) * 32);     \
    }                                                                        \
  } while (0)

#define MFMARB(BUF, RB)                                                      \
  do {                                                                       \
    _Pragma("unroll")                                                        \
    for (int kk = 0; kk < SLICE; ++kk) {                                     \
      const int kb_ = wbase + kk;                                            \
      const bool isx_ = kb_ < NXB;                                           \
      const f16x8 af_ = BUF[kk];                                             \
      aR[RB] = __builtin_amdgcn_mfma_f32_16x16x32_f16(af_, wfR[kk], aR[RB], 0, 0, 0); \
      aZ[RB] = __builtin_amdgcn_mfma_f32_16x16x32_f16(af_, wfZ[kk], aZ[RB], 0, 0, 0); \
      const f16x8 z8_ = {0, 0, 0, 0, 0, 0, 0, 0};                            \
      const f16x8 afx_ = isx_ ? af_ : z8_;                                   \
      const f16x8 afh_ = isx_ ? z8_ : af_;                                   \
      aNX[RB] = __builtin_amdgcn_mfma_f32_16x16x32_f16(afx_, wfN[kk], aNX[RB], 0, 0, 0); \
      aNH[RB] = __builtin_amdgcn_mfma_f32_16x16x32_f16(afh_, wfN[kk], aNH[RB], 0, 0, 0); \
    }                                                                        \
  } while (0)

      {
        f16x8 bufA[SLICE], bufB[SLICE];
        LOADRB(bufA, 0);
        LOADRB(bufB, 1);
        MFMARB(bufA, 0);
        LOADRB(bufA, 2);
        MFMARB(bufB, 1);
        LOADRB(bufB, 3);
        MFMARB(bufA, 2);
        MFMARB(bufB, 3);
      }
#undef LOADRB
#undef MFMARB

      // ---- two-phase scalar-LDS reduction (R11/R12/R13-verified) ----
      if (wave < 2) {
#pragma unroll
        for (int rb = 0; rb < 4; ++rb)
#pragma unroll
          for (int i = 0; i < 4; ++i) {
            red[ridx(0 + wave, rb, i, lane)] = aR[rb][i];
            red[ridx(2 + wave, rb, i, lane)] = aZ[rb][i];
            red[ridx(4 + wave, rb, i, lane)] = aNX[rb][i];
            red[ridx(6 + wave, rb, i, lane)] = aNH[rb][i];
          }
      }
      __syncthreads();
      if (wave >= 2) {
        const int p = wave - 2;
#pragma unroll
        for (int rb = 0; rb < 4; ++rb)
#pragma unroll
          for (int i = 0; i < 4; ++i) {
            red[ridx(0 + p, rb, i, lane)] += aR[rb][i];
            red[ridx(2 + p, rb, i, lane)] += aZ[rb][i];
            red[ridx(4 + p, rb, i, lane)] += aNX[rb][i];
            red[ridx(6 + p, rb, i, lane)] += aNH[rb][i];
          }
      }
      __syncthreads();

      {
        // Epilogue: h-master in LDS (stride 17 kills bank aliasing);
        // ho via sc1; final h32f via sc1 f32.
#pragma unroll
        for (int i = 0; i < 4; ++i) {
          const int b = wave * 16 + kg * 4 + i;
          const float R  = red[ridx(0, wave, i, lane)] + red[ridx(1, wave, i, lane)];
          const float Z  = red[ridx(2, wave, i, lane)] + red[ridx(3, wave, i, lane)];
          const float NX = red[ridx(4, wave, i, lane)] + red[ridx(5, wave, i, lane)];
          const float NH = red[ridx(6, wave, i, lane)] + red[ridx(7, wave, i, lane)];
          const float r = sigmoid_f(R + bir + bhr);
          const float zz = sigmoid_f(Z + biz + bhz);
          const float nn = tanh_f(NX + bin_ + r * (NH + bhn));
          const float hp = hlds[b * 17 + jc];
          const float hnew = (1.0f - zz) * nn + zz * hp;
          hlds[b * 17 + jc] = hnew;
          astore2(&ho[(size_t)b * H_ + j], (f16)hnew);
          if (is_last && t == T_ - 1) astore4(&a.h32f[(size_t)b * H_ + j], hnew);
        }
      }
    }
    light_barrier(a.flags, u + 1);
  }
}

__global__ void __launch_bounds__(NTHR, 1) gru_pipeline(Args a) {
  __shared__ float red[8 * 4 * 4 * 64];   // 32 KiB scalar f32 (R9-verified)
  __shared__ float hlds[B_ * 17];         // 4.25 KiB h-master (LDS, no dirty L2)

  const int tid = threadIdx.x;
  const int gtid = blockIdx.x * NTHR + tid;
  const int NT = NWG * NTHR;

  // ================= Phase 0: prologue (R6/R9/R11/R12 verbatim) ===========
  {
    const int nf4 = B_ * T_ * IN0_ / 4;
    for (int i = gtid; i < nf4; i += NT) {
      int k4 = i & 127;
      int q = i >> 7;
      int b = q & 63;
      int t = q >> 6;
      const float4 v = *(const float4*)(a.x + ((size_t)b * T_ + t) * IN0_ + k4 * 4);
      f16x4 o;
      o[0] = (f16)v.x; o[1] = (f16)v.y; o[2] = (f16)v.z; o[3] = (f16)v.w;
      *(f16x4*)(a.x16 + (size_t)i * 4) = o;
    }
  }
  {
    f16x8 z8 = {0, 0, 0, 0, 0, 0, 0, 0};
    for (int i = gtid; i < 4 * 2 * B_ * H_ / 8; i += NT)
      ((f16x8*)a.houts)[i] = z8;
  }
  for (int i = tid; i < B_ * 17; i += NTHR) hlds[i] = 0.f;
  for (int l = 0; l < 4; ++l) {
    const int In = l ? H_ : IN0_;
    const int K = In + H_;
    const int NKB = K / 32;
    const float* Wih = a.Wih[l];
    const float* Whh = a.Whh[l];
    f16* wp = a.wpack + WOFF_[l];
    const int nunits = 3 * H_ * K / 8;
    for (int uu = gtid; uu < nunits; uu += NT) {
      int lane = uu & 63;
      int q = uu >> 6;
      int kb = q % NKB; q /= NKB;
      int gate = q % 3;
      int subb = q / 3;
      int j = subb * 16 + (lane & 15);
      int g = gate * H_ + j;
      int k = kb * 32 + (lane >> 4) * 8;
      const float* src = (k < In) ? (Wih + (size_t)g * In + k)
                                  : (Whh + (size_t)g * H_ + (k - In));
      f16x8 vv;
#pragma unroll
      for (int e = 0; e < 8; ++e) vv[e] = (f16)src[e];
      ((f16x8*)wp)[uu] = vv;
    }
  }

  heavy_barrier(a.bar);   // wbl2+inv once: x16/wpack/houts-zeros now stable

  // ================= Phase 1: pipelined recurrence ========================
  const int wg = blockIdx.x;
  const int layer = wg >> 6;
  const int sub = wg & 63;

  if (layer == 0) run_layer<IN0_>(a, layer, sub, false, red, hlds);
  else            run_layer<H_>(a, layer, sub, layer == 3, red, hlds);

  heavy_barrier(a.bar);   // full visibility for h32f before FC

  // ================= Phase 2: final FC (verbatim) ========================
  for (int o = gtid; o < B_ * C_; o += NT) {
    const int b = o / C_;
    const int c = o - b * C_;
    const float* hv = a.h32f + (size_t)b * H_;
    const float* wv = a.fcw + (size_t)c * H_;
    float s = a.fcb[c];
    for (int k = 0; k < H_; k += 4) {
      const float4 h4 = *(const float4*)(hv + k);
      const float4 w4 = *(const float4*)(wv + k);
      s = fmaf(h4.x, w4.x, s);
      s = fmaf(h4.y, w4.y, s);
      s = fmaf(h4.z, w4.z, s);
      s = fmaf(h4.w, w4.w, s);
    }
    a.out[o] = s;
  }
}

extern "C" void kernel_launch(void* const* d_in, const int* in_sizes, int n_in,
                              void* d_out, int out_size, void* d_ws, size_t ws_size,
                              hipStream_t stream) {
  Args a;
  a.x = (const float*)d_in[0];
  for (int l = 0; l < 4; ++l) {
    a.Wih[l] = (const float*)d_in[1 + 4 * l];
    a.Whh[l] = (const float*)d_in[2 + 4 * l];
    a.bih[l] = (const float*)d_in[3 + 4 * l];
    a.bhh[l] = (const float*)d_in[4 + 4 * l];
  }
  a.fcw = (const float*)d_in[17];
  a.fcb = (const float*)d_in[18];
  a.out = (float*)d_out;

  char* ws = (char*)d_ws;
  size_t off = 0;
  a.wpack = (f16*)(ws + off); off += 23592960ul * 2;                  // 45 MiB
  a.x16   = (f16*)(ws + off); off += 16777216ul * 2;                  // 32 MiB
  a.houts = (f16*)(ws + off); off += 4ul * 2 * B_ * H_ * 2;           // 1 MiB
  a.h32f  = (float*)(ws + off); off += (size_t)B_ * H_ * 4;           // 256 KiB
  a.flags = (int*)(ws + off); off += (NWG * 32 + 32) * sizeof(int);   // 33 KiB
  a.bar   = (int*)(ws + off); off += 256;

  hipMemsetAsync(a.flags, 0, (NWG * 32 + 32) * sizeof(int) + 256, stream);

  void* params[] = { &a };
  hipError_t err = hipLaunchCooperativeKernel((void*)gru_pipeline, dim3(NWG),
                                              dim3(NTHR), params, 0, stream);
  if (err != hipSuccess) {
    gru_pipeline<<<dim3(NWG), dim3(NTHR), 0, stream>>>(a);
  }
}

// Round 15
// 11283.105 us; speedup vs baseline: 4.6013x; 1.0241x over previous
//
#include <hip/hip_runtime.h>

#define B_ 64
#define T_ 512
#define IN0_ 512
#define H_ 1024
#define C_ 1000
#define NWG 256
#define NTHR 256

typedef _Float16 f16;
typedef _Float16 f16x8 __attribute__((ext_vector_type(8)));
typedef _Float16 f16x4 __attribute__((ext_vector_type(4)));
typedef float f32x4 __attribute__((ext_vector_type(4)));

struct Args {
  const float* x;
  const float* Wih[4];
  const float* Whh[4];
  const float* bih[4];
  const float* bhh[4];
  const float* fcw;
  const float* fcb;
  float* out;
  f16* wpack;
  f16* x16;     // [T][B][512] f16
  f16* houts;   // [4 layers][2 parity][64][1024] f16 (sc1-written, 8B chunks)
  float* h32f;  // [64][1024] f32 final hidden of layer 3 (sc1-written)
  int* flags;   // NWG flags, padded 128B apart (all-to-all barrier)
  int* bar;     // [0]=count, [1]=generation (heavy barrier)
};

__device__ __forceinline__ float sigmoid_f(float x) {
  return 1.0f / (1.0f + __expf(-x));
}
__device__ __forceinline__ float tanh_f(float x) {
  return 1.0f - 2.0f / (__expf(2.0f * x) + 1.0f);
}

// HEAVY barrier — R1 VERBATIM (HW-verified). Used twice only.
__device__ __forceinline__ void heavy_barrier(int* bar) {
  __threadfence();
  __syncthreads();
  if (threadIdx.x == 0) {
    int* cnt = bar;
    int* gen = bar + 1;
    int g = __hip_atomic_load(gen, __ATOMIC_RELAXED, __HIP_MEMORY_SCOPE_AGENT);
    int v = __hip_atomic_fetch_add(cnt, 1, __ATOMIC_ACQ_REL, __HIP_MEMORY_SCOPE_AGENT);
    if (v == NWG - 1) {
      __hip_atomic_store(cnt, 0, __ATOMIC_RELAXED, __HIP_MEMORY_SCOPE_AGENT);
      __hip_atomic_store(gen, g + 1, __ATOMIC_RELEASE, __HIP_MEMORY_SCOPE_AGENT);
    } else {
      int cur;
      do {
        __builtin_amdgcn_s_sleep(2);
        cur = __hip_atomic_load(gen, __ATOMIC_ACQUIRE, __HIP_MEMORY_SCOPE_AGENT);
      } while (cur == g);
    }
  }
  __syncthreads();
  __threadfence();
}

// LIGHT per-step barrier v4 — ALL-TO-ALL flags, ONE L3 round trip.
// Producer ordering (R12/R13-verified): sc1 data stores + vmcnt(0) drain in
// every thread BEFORE the flag store -> data is at the coherent L3 when the
// flag becomes visible. Detection: thread i of EVERY WG polls flags[i]
// directly (relaxed sc1 loads) — no WG0 aggregation, no `go` broadcast.
// Same one-barrier-per-step safety invariant as before: a WG's flag for
// step s is stored only after its step s-1 reads completed.
__device__ __forceinline__ void light_barrier(int* flags, int step) {
  asm volatile("s_waitcnt vmcnt(0) lgkmcnt(0)" ::: "memory");
  __syncthreads();
  if (threadIdx.x == 0)
    __hip_atomic_store(flags + blockIdx.x * 32, step, __ATOMIC_RELAXED,
                       __HIP_MEMORY_SCOPE_AGENT);
  {
    const int t = threadIdx.x;
    if (t < NWG && t != (int)blockIdx.x) {
      while (__hip_atomic_load(flags + t * 32, __ATOMIC_RELAXED,
                               __HIP_MEMORY_SCOPE_AGENT) < step)
        __builtin_amdgcn_s_sleep(2);
    }
  }
  __syncthreads();
}

// Coherent 16B fragment load — R8..R13 VERBATIM (HW-verified).
union U16B { unsigned long long u[2]; f16x8 v; };
__device__ __forceinline__ f16x8 aload16(const f16* p) {
  unsigned long long* q = (unsigned long long*)p;
  U16B r;
  r.u[0] = __hip_atomic_load(q,     __ATOMIC_RELAXED, __HIP_MEMORY_SCOPE_AGENT);
  r.u[1] = __hip_atomic_load(q + 1, __ATOMIC_RELAXED, __HIP_MEMORY_SCOPE_AGENT);
  return r.v;
}

// Coherent 8B store (sc1, write-through to L3) — coalesced ho writes.
__device__ __forceinline__ void astore8(f16* p, unsigned long long v) {
  __hip_atomic_store((unsigned long long*)p, v, __ATOMIC_RELAXED,
                     __HIP_MEMORY_SCOPE_AGENT);
}
union UF32 { float f; unsigned u; };
__device__ __forceinline__ void astore4(float* p, float v) {
  UF32 c; c.f = v;
  __hip_atomic_store((unsigned*)p, c.u, __ATOMIC_RELAXED,
                     __HIP_MEMORY_SCOPE_AGENT);
}

// Packed-weight layer offsets in f16 elements (R6-verified repack layout).
__constant__ __device__ const size_t WOFF_[4] = {0ul, 4718592ul, 11010048ul, 17301504ul};

// LDS reduction slot (R9-verified scalar layout; banks R:0/1 Z:2/3 NX:4/5 NH:6/7).
__device__ __forceinline__ int ridx(int bank, int rb, int i, int lane) {
  return ((bank * 4 + rb) * 4 + i) * 64 + lane;
}

// R13-VERIFIED K-slice layer. Changes: (1) h-master in LDS (R14-verified),
// (2) epilogue stages h' in an LDS tile and emits coalesced 8B sc1 stores
// (bit-identical data, 4x fewer device-scope store ops), (3) all-to-all
// barrier. Load path = R13 verbatim (aload16 h-part / xprev; ordinary x16).
template <int IN, bool XA>
__device__ void run_layer(const Args& a, int layer, int sub, bool is_last,
                          float* red, float* hlds, f16* hstage) {
  constexpr int NKB = (IN + H_) / 32;   // 48 (layer0) or 64
  constexpr int NXB = IN / 32;          // 16 or 32
  constexpr int SLICE = NKB / 4;        // 12 or 16

  const int tid = threadIdx.x;
  const int wave = tid >> 6;            // 0..3
  const int lane = tid & 63;
  const int jc = lane & 15;
  const int kg = lane >> 4;
  const int j = sub * 16 + jc;
  const int wbase = wave * SLICE;

  const float bir = a.bih[layer][j], bhr = a.bhh[layer][j];
  const float biz = a.bih[layer][H_ + j], bhz = a.bhh[layer][H_ + j];
  const float bin_ = a.bih[layer][2 * H_ + j], bhn = a.bhh[layer][2 * H_ + j];

  // ---- gather this wave's K-slice weights, all 3 gates (R11-verified) ----
  const f16x8* wpb = (const f16x8*)(a.wpack + WOFF_[layer] +
                                    (size_t)sub * 3 * NKB * 512) + lane;
  f16x8 wfR[SLICE], wfZ[SLICE], wfN[SLICE];
#pragma unroll
  for (int kk = 0; kk < SLICE; ++kk) {
    wfR[kk] = wpb[(size_t)(0 * NKB + wbase + kk) * 64];
    wfZ[kk] = wpb[(size_t)(1 * NKB + wbase + kk) * 64];
    wfN[kk] = wpb[(size_t)(2 * NKB + wbase + kk) * 64];
  }

  f16* hout0 = a.houts + (size_t)(layer * 2 + 0) * B_ * H_;
  f16* hout1 = hout0 + B_ * H_;
  const f16* xp0 = layer ? a.houts + (size_t)((layer - 1) * 2) * B_ * H_ : (const f16*)nullptr;
  const f16* xp1 = layer ? xp0 + B_ * H_ : (const f16*)nullptr;

  for (int u = 0; u < T_ + 3; ++u) {
    const int t = u - layer;
    if (t >= 0 && t < T_) {
      const f16* xbase = (IN == IN0_) ? (a.x16 + (size_t)t * B_ * IN0_)
                                      : ((t & 1) ? xp1 : xp0);
      const f16* hbase = ((t + 1) & 1) ? hout1 : hout0;
      f16* ho = (t & 1) ? hout1 : hout0;

      f32x4 aR[4], aZ[4], aNX[4], aNH[4];
#pragma unroll
      for (int rb = 0; rb < 4; ++rb) {
        aR[rb] = 0.f; aZ[rb] = 0.f; aNX[rb] = 0.f; aNH[rb] = 0.f;
      }

#define LOADRB(BUF, RB)                                                      \
  do {                                                                       \
    const int arow_ = (RB) * 16 + jc;                                        \
    const f16* xrow_ = xbase + (size_t)arow_ * IN + kg * 8;                  \
    const f16* hrow_ = hbase + (size_t)arow_ * H_ + kg * 8;                  \
    _Pragma("unroll")                                                        \
    for (int kk = 0; kk < SLICE; ++kk) {                                     \
      const int kb_ = wbase + kk;                                            \
      if (kb_ < NXB) {                                                       \
        if constexpr (XA) BUF[kk] = aload16(xrow_ + kb_ * 32);               \
        else              BUF[kk] = *(const f16x8*)(xrow_ + kb_ * 32);       \
      } else {                                                               \
        BUF[kk] = aload16(hrow_ + (kb_ - NXB) * 32);                         \
      }                                                                      \
    }                                                                        \
  } while (0)

#define MFMARB(BUF, RB)                                                      \
  do {                                                                       \
    _Pragma("unroll")                                                        \
    for (int kk = 0; kk < SLICE; ++kk) {                                     \
      const int kb_ = wbase + kk;                                            \
      const bool isx_ = kb_ < NXB;                                           \
      const f16x8 af_ = BUF[kk];                                             \
      aR[RB] = __builtin_amdgcn_mfma_f32_16x16x32_f16(af_, wfR[kk], aR[RB], 0, 0, 0); \
      aZ[RB] = __builtin_amdgcn_mfma_f32_16x16x32_f16(af_, wfZ[kk], aZ[RB], 0, 0, 0); \
      const f16x8 z8_ = {0, 0, 0, 0, 0, 0, 0, 0};                            \
      const f16x8 afx_ = isx_ ? af_ : z8_;                                   \
      const f16x8 afh_ = isx_ ? z8_ : af_;                                   \
      aNX[RB] = __builtin_amdgcn_mfma_f32_16x16x32_f16(afx_, wfN[kk], aNX[RB], 0, 0, 0); \
      aNH[RB] = __builtin_amdgcn_mfma_f32_16x16x32_f16(afh_, wfN[kk], aNH[RB], 0, 0, 0); \
    }                                                                        \
  } while (0)

      {
        f16x8 bufA[SLICE], bufB[SLICE];
        LOADRB(bufA, 0);
        LOADRB(bufB, 1);
        MFMARB(bufA, 0);
        LOADRB(bufA, 2);
        MFMARB(bufB, 1);
        LOADRB(bufB, 3);
        MFMARB(bufA, 2);
        MFMARB(bufB, 3);
      }
#undef LOADRB
#undef MFMARB

      // ---- two-phase scalar-LDS reduction (R11..R14-verified) ----
      if (wave < 2) {
#pragma unroll
        for (int rb = 0; rb < 4; ++rb)
#pragma unroll
          for (int i = 0; i < 4; ++i) {
            red[ridx(0 + wave, rb, i, lane)] = aR[rb][i];
            red[ridx(2 + wave, rb, i, lane)] = aZ[rb][i];
            red[ridx(4 + wave, rb, i, lane)] = aNX[rb][i];
            red[ridx(6 + wave, rb, i, lane)] = aNH[rb][i];
          }
      }
      __syncthreads();
      if (wave >= 2) {
        const int p = wave - 2;
#pragma unroll
        for (int rb = 0; rb < 4; ++rb)
#pragma unroll
          for (int i = 0; i < 4; ++i) {
            red[ridx(0 + p, rb, i, lane)] += aR[rb][i];
            red[ridx(2 + p, rb, i, lane)] += aZ[rb][i];
            red[ridx(4 + p, rb, i, lane)] += aNX[rb][i];
            red[ridx(6 + p, rb, i, lane)] += aNH[rb][i];
          }
      }
      __syncthreads();

      // ---- epilogue: gate math -> LDS stage (h-master in hlds) ----
      {
#pragma unroll
        for (int i = 0; i < 4; ++i) {
          const int b = wave * 16 + kg * 4 + i;
          const float R  = red[ridx(0, wave, i, lane)] + red[ridx(1, wave, i, lane)];
          const float Z  = red[ridx(2, wave, i, lane)] + red[ridx(3, wave, i, lane)];
          const float NX = red[ridx(4, wave, i, lane)] + red[ridx(5, wave, i, lane)];
          const float NH = red[ridx(6, wave, i, lane)] + red[ridx(7, wave, i, lane)];
          const float r = sigmoid_f(R + bir + bhr);
          const float zz = sigmoid_f(Z + biz + bhz);
          const float nn = tanh_f(NX + bin_ + r * (NH + bhn));
          const float hp = hlds[b * 17 + jc];
          const float hnew = (1.0f - zz) * nn + zz * hp;
          hlds[b * 17 + jc] = hnew;
          hstage[b * 20 + jc] = (f16)hnew;
          if (is_last && t == T_ - 1) astore4(&a.h32f[(size_t)b * H_ + j], hnew);
        }
      }
      __syncthreads();
      // ---- coalesced ho write: one aligned 8B sc1 store per thread ----
      {
        const int b = tid >> 2;          // 0..63
        const int c = tid & 3;           // 0..3 (8B chunk within 16 f16)
        const unsigned long long v =
            *(const unsigned long long*)&hstage[b * 20 + c * 4];
        astore8(&ho[(size_t)b * H_ + sub * 16 + c * 4], v);
      }
    }
    light_barrier(a.flags, u + 1);
  }
}

__global__ void __launch_bounds__(NTHR, 1) gru_pipeline(Args a) {
  __shared__ float red[8 * 4 * 4 * 64];   // 32 KiB scalar f32 (R9-verified)
  __shared__ float hlds[B_ * 17];         // 4.25 KiB h-master (R14-verified)
  __shared__ f16 hstage[B_ * 20];         // 2.5 KiB h' staging (8B-aligned rows)

  const int tid = threadIdx.x;
  const int gtid = blockIdx.x * NTHR + tid;
  const int NT = NWG * NTHR;

  // ================= Phase 0: prologue (R6..R14 verbatim) =================
  {
    const int nf4 = B_ * T_ * IN0_ / 4;
    for (int i = gtid; i < nf4; i += NT) {
      int k4 = i & 127;
      int q = i >> 7;
      int b = q & 63;
      int t = q >> 6;
      const float4 v = *(const float4*)(a.x + ((size_t)b * T_ + t) * IN0_ + k4 * 4);
      f16x4 o;
      o[0] = (f16)v.x; o[1] = (f16)v.y; o[2] = (f16)v.z; o[3] = (f16)v.w;
      *(f16x4*)(a.x16 + (size_t)i * 4) = o;
    }
  }
  {
    f16x8 z8 = {0, 0, 0, 0, 0, 0, 0, 0};
    for (int i = gtid; i < 4 * 2 * B_ * H_ / 8; i += NT)
      ((f16x8*)a.houts)[i] = z8;
  }
  for (int i = tid; i < B_ * 17; i += NTHR) hlds[i] = 0.f;
  for (int l = 0; l < 4; ++l) {
    const int In = l ? H_ : IN0_;
    const int K = In + H_;
    const int NKB = K / 32;
    const float* Wih = a.Wih[l];
    const float* Whh = a.Whh[l];
    f16* wp = a.wpack + WOFF_[l];
    const int nunits = 3 * H_ * K / 8;
    for (int uu = gtid; uu < nunits; uu += NT) {
      int lane = uu & 63;
      int q = uu >> 6;
      int kb = q % NKB; q /= NKB;
      int gate = q % 3;
      int subb = q / 3;
      int j = subb * 16 + (lane & 15);
      int g = gate * H_ + j;
      int k = kb * 32 + (lane >> 4) * 8;
      const float* src = (k < In) ? (Wih + (size_t)g * In + k)
                                  : (Whh + (size_t)g * H_ + (k - In));
      f16x8 vv;
#pragma unroll
      for (int e = 0; e < 8; ++e) vv[e] = (f16)src[e];
      ((f16x8*)wp)[uu] = vv;
    }
  }

  heavy_barrier(a.bar);   // wbl2+inv once: x16/wpack/houts-zeros now stable

  // ================= Phase 1: pipelined recurrence ========================
  const int wg = blockIdx.x;
  const int layer = wg >> 6;
  const int sub = wg & 63;

  if (layer == 0) run_layer<IN0_, false>(a, layer, sub, false, red, hlds, hstage);
  else            run_layer<H_, true>(a, layer, sub, layer == 3, red, hlds, hstage);

  heavy_barrier(a.bar);   // full visibility for h32f before FC

  // ================= Phase 2: final FC (verbatim) ========================
  for (int o = gtid; o < B_ * C_; o += NT) {
    const int b = o / C_;
    const int c = o - b * C_;
    const float* hv = a.h32f + (size_t)b * H_;
    const float* wv = a.fcw + (size_t)c * H_;
    float s = a.fcb[c];
    for (int k = 0; k < H_; k += 4) {
      const float4 h4 = *(const float4*)(hv + k);
      const float4 w4 = *(const float4*)(wv + k);
      s = fmaf(h4.x, w4.x, s);
      s = fmaf(h4.y, w4.y, s);
      s = fmaf(h4.z, w4.z, s);
      s = fmaf(h4.w, w4.w, s);
    }
    a.out[o] = s;
  }
}

extern "C" void kernel_launch(void* const* d_in, const int* in_sizes, int n_in,
                              void* d_out, int out_size, void* d_ws, size_t ws_size,
                              hipStream_t stream) {
  Args a;
  a.x = (const float*)d_in[0];
  for (int l = 0; l < 4; ++l) {
    a.Wih[l] = (const float*)d_in[1 + 4 * l];
    a.Whh[l] = (const float*)d_in[2 + 4 * l];
    a.bih[l] = (const float*)d_in[3 + 4 * l];
    a.bhh[l] = (const float*)d_in[4 + 4 * l];
  }
  a.fcw = (const float*)d_in[17];
  a.fcb = (const float*)d_in[18];
  a.out = (float*)d_out;

  char* ws = (char*)d_ws;
  size_t off = 0;
  a.wpack = (f16*)(ws + off); off += 23592960ul * 2;                  // 45 MiB
  a.x16   = (f16*)(ws + off); off += 16777216ul * 2;                  // 32 MiB
  a.houts = (f16*)(ws + off); off += 4ul * 2 * B_ * H_ * 2;           // 1 MiB
  a.h32f  = (float*)(ws + off); off += (size_t)B_ * H_ * 4;           // 256 KiB
  a.flags = (int*)(ws + off); off += (NWG * 32 + 32) * sizeof(int);   // 33 KiB
  a.bar   = (int*)(ws + off); off += 256;

  hipMemsetAsync(a.flags, 0, (NWG * 32 + 32) * sizeof(int) + 256, stream);

  void* params[] = { &a };
  hipError_t err = hipLaunchCooperativeKernel((void*)gru_pipeline, dim3(NWG),
                                              dim3(NTHR), params, 0, stream);
  if (err != hipSuccess) {
    gru_pipeline<<<dim3(NWG), dim3(NTHR), 0, stream>>>(a);
  }
}